// Round 2
// 488.156 us; speedup vs baseline: 1.1019x; 1.1019x over previous
//
#include <hip/hip_runtime.h>
#include <hip/hip_bf16.h>

typedef __attribute__((ext_vector_type(8))) __bf16 bf16x8;
typedef __attribute__((ext_vector_type(4))) float f32x4;
typedef __attribute__((ext_vector_type(4))) short sh4;
typedef __attribute__((ext_vector_type(8))) short sh8;

#define MFMA(a, b, c) __builtin_amdgcn_mfma_f32_16x16x32_bf16(a, b, c, 0, 0, 0)

#if __has_builtin(__builtin_amdgcn_exp2f)
#define EXP2(x) __builtin_amdgcn_exp2f(x)
#else
#define EXP2(x) exp2f(x)
#endif

// K=32 B-frag / V-frag pairing: slot s = lg*8 + c*4 + r <-> kv-row c*16 + lg*4 + r.
// (kv is a contraction index; P and V use the same permutation, so this is exact.)
union P8 { struct { sh4 lo, hi; } p; sh8 v; };

// Packed f32->bf16 (v_cvt_pk_bf16_f32): 4 floats -> sh4 in 2 insts.
__device__ __forceinline__ sh4 pk4(float a, float b, float c, float d) {
    __hip_bfloat162 lo = __float22bfloat162_rn(float2{a, b});
    __hip_bfloat162 hi = __float22bfloat162_rn(float2{c, d});
    union { struct { __hip_bfloat162 lo, hi; } p; sh4 s; } u;
    u.p.lo = lo; u.p.hi = hi;
    return u.s;
}

__device__ __forceinline__ float ldany(const void* p, size_t i, bool f32) {
    return f32 ? ((const float*)p)[i] : (float)(((const __bf16*)p)[i]);
}

// ---------------------------------------------------------------------------
// Merged detect + small-conversions (one launch). offsets: bq 1024, bk 2048,
// bv 3072, bo 4096, b1 5120(4096), b2 9216, ln1a 10240..ln2b 10243.
__global__ void prep_k(const void* wq, float* flag,
                       const void* bq, const void* bk, const void* bv, const void* bo,
                       const void* b1, const void* b2,
                       const void* l1a, const void* l1b, const void* l2a, const void* l2b,
                       __bf16* dst) {
    __shared__ float red[256];
    __shared__ float fls;
    int tid = threadIdx.x;
    const __bf16* p = (const __bf16*)wq;
    float mx = 0.f;
    for (int i = tid; i < 1024; i += 256) {
        float v = (float)p[i];
        if (v != v) mx = 2.f;
        v = fabsf(v);
        if (v > mx) mx = v;
    }
    red[tid] = mx;
    __syncthreads();
    for (int s = 128; s > 0; s >>= 1) {
        if (tid < s) red[tid] = fmaxf(red[tid], red[tid + s]);
        __syncthreads();
    }
    if (tid == 0) { fls = (red[0] > 1.0f) ? 1.f : 0.f; *flag = fls; }
    __syncthreads();
    bool f32 = fls > 0.5f;
    const void* srcs[10] = {bq, bk, bv, bo, b1, b2, l1a, l1b, l2a, l2b};
    const int offs[10] = {1024, 2048, 3072, 4096, 5120, 9216, 10240, 10241, 10242, 10243};
    const int ns[10]   = {1024, 1024, 1024, 1024, 4096, 1024, 1, 1, 1, 1};
    for (int t = 0; t < 10; ++t)
        for (int j = tid; j < ns[t]; j += blockDim.x)
            dst[offs[t] + j] = (__bf16)ldany(srcs[t], j, f32);
}

// ---------------------------------------------------------------------------
__device__ __forceinline__ void tr_body(const void* in, __bf16* out, int R, int C, bool f32,
                                        int bx, int by, int x, int y) {
    __shared__ __bf16 t[32][33];
    for (int i = 0; i < 32; i += 8)
        t[y + i][x] = (__bf16)ldany(in, (size_t)(by + y + i) * C + bx + x, f32);
    __syncthreads();
    for (int i = 0; i < 32; i += 8)
        out[(size_t)(bx + y + i) * R + by + x] = t[x][y + i];
}

__global__ void transpose_cvt(const void* in, __bf16* out, int R, int C, const float* flag) {
    tr_body(in, out, R, C, *flag > 0.5f, blockIdx.x * 32, blockIdx.y * 32,
            threadIdx.x, threadIdx.y);
}

__global__ void transpose4_cvt(const void* i0, const void* i1, const void* i2, const void* i3,
                               __bf16* o0, __bf16* o1, __bf16* o2, __bf16* o3,
                               const float* flag) {
    const void* in = blockIdx.z == 0 ? i0 : blockIdx.z == 1 ? i1 : blockIdx.z == 2 ? i2 : i3;
    __bf16* out = blockIdx.z == 0 ? o0 : blockIdx.z == 1 ? o1 : blockIdx.z == 2 ? o2 : o3;
    tr_body(in, out, 1024, 1024, *flag > 0.5f, blockIdx.x * 32, blockIdx.y * 32,
            threadIdx.x, threadIdx.y);
}

// ---------------------------------------------------------------------------
__global__ __launch_bounds__(256) void layernorm_k(const void* x, int xmode, const float* flag,
                                                   __bf16* out,
                                                   const __bf16* alpha, const __bf16* beta) {
    int row = blockIdx.x * 4 + (threadIdx.x >> 6);
    int lane = threadIdx.x & 63;
    bool f32 = xmode && (*flag > 0.5f);
    float v[16];
    if (f32) {
        const float4* xr = (const float4*)((const float*)x + (size_t)row * 1024 + lane * 16);
#pragma unroll
        for (int q = 0; q < 4; ++q) {
            float4 r = xr[q];
            v[q * 4 + 0] = r.x; v[q * 4 + 1] = r.y; v[q * 4 + 2] = r.z; v[q * 4 + 3] = r.w;
        }
    } else {
        const __bf16* xr = (const __bf16*)x + (size_t)row * 1024 + lane * 16;
        bf16x8 h0 = *(const bf16x8*)xr;
        bf16x8 h1 = *(const bf16x8*)(xr + 8);
#pragma unroll
        for (int i = 0; i < 8; ++i) { v[i] = (float)h0[i]; v[8 + i] = (float)h1[i]; }
    }
    float s = 0.f, ss = 0.f;
#pragma unroll
    for (int i = 0; i < 16; ++i) { s += v[i]; ss += v[i] * v[i]; }
#pragma unroll
    for (int o = 1; o < 64; o <<= 1) { s += __shfl_xor(s, o); ss += __shfl_xor(ss, o); }
    float mu = s * (1.f / 1024.f);
    float var = (ss - 1024.f * mu * mu) * (1.f / 1023.f);
    float inv = 1.f / (sqrtf(var) + 1e-6f);
    float al = (float)alpha[0], be = (float)beta[0];
    bf16x8 o0, o1;
#pragma unroll
    for (int i = 0; i < 8; ++i) {
        o0[i] = (__bf16)((v[i] - mu) * inv * al + be);
        o1[i] = (__bf16)((v[8 + i] - mu) * inv * al + be);
    }
    __bf16* orow = out + (size_t)row * 1024;
    *(bf16x8*)(orow + lane * 16) = o0;
    *(bf16x8*)(orow + lane * 16 + 8) = o1;
}

// Swizzled-tile store helpers: 64x64 tiles, chunk (8 halves) XOR'd by row&7.
__device__ __forceinline__ void swz_store(__bf16* buf, int hh, int ktt, int rr2, int cc2,
                                          float v) {
    size_t off = (((size_t)hh * 64 + ktt) << 12) + rr2 * 64 +
                 (((cc2 >> 3) ^ (rr2 & 7)) << 3) + (cc2 & 7);
    buf[off] = (__bf16)v;
}

// ---------------------------------------------------------------------------
// GEMM 128x128 (256 thr, m97). swz: 0 none; 1 = cols>=1024 are K -> swzbuf.
// ---------------------------------------------------------------------------
__global__ __launch_bounds__(256) void gemm_bt(const __bf16* __restrict__ A, int lda,
                                               const __bf16* __restrict__ Bt, int ldb,
                                               const __bf16* __restrict__ bias_n,
                                               const __bf16* __restrict__ bias_m,
                                               const void* res, int res_mode,
                                               const float* flag,
                                               void* C, int out_pf,
                                               int M, int N, int K, int relu,
                                               __bf16* swzbuf, int swz) {
    __shared__ __bf16 As[128 * 32];
    __shared__ __bf16 Bs[128 * 32];
    const int tid = threadIdx.x;
    const int m0 = blockIdx.y * 128;
    const int n0 = blockIdx.x * 128;
    const int w = tid >> 6, lane = tid & 63;
    const int wr = (w >> 1) * 64, wc = (w & 1) * 64;
    const int lm = lane & 15, lg = lane >> 4;
    const bool f32 = *flag > 0.5f;
    const bool rf32 = (res_mode == 2) && f32;
    const bool of32 = out_pf && f32;

    f32x4 acc[4][4] = {};
    for (int k0 = 0; k0 < K; k0 += 32) {
#pragma unroll
        for (int i = 0; i < 2; ++i) {
            int c = i * 256 + tid;
            int row = c >> 2, kk = (c & 3) * 8;
            __builtin_amdgcn_global_load_lds(
                (const __attribute__((address_space(1))) void*)(A + (size_t)(m0 + row) * lda + k0 + kk),
                (__attribute__((address_space(3))) void*)(As + c * 8), 16, 0, 0);
            __builtin_amdgcn_global_load_lds(
                (const __attribute__((address_space(1))) void*)(Bt + (size_t)(n0 + row) * ldb + k0 + kk),
                (__attribute__((address_space(3))) void*)(Bs + c * 8), 16, 0, 0);
        }
        __syncthreads();
        bf16x8 a[4], b[4];
#pragma unroll
        for (int t = 0; t < 4; ++t)
            a[t] = *(const bf16x8*)(As + (wr + t * 16 + lm) * 32 + lg * 8);
#pragma unroll
        for (int t = 0; t < 4; ++t)
            b[t] = *(const bf16x8*)(Bs + (wc + t * 16 + lm) * 32 + lg * 8);
#pragma unroll
        for (int mt = 0; mt < 4; ++mt)
#pragma unroll
            for (int nt = 0; nt < 4; ++nt)
                acc[mt][nt] = MFMA(a[mt], b[nt], acc[mt][nt]);
        __syncthreads();
    }
#pragma unroll
    for (int mt = 0; mt < 4; ++mt) {
#pragma unroll
        for (int nt = 0; nt < 4; ++nt) {
            int col = n0 + wc + nt * 16 + lm;
            float bn = bias_n ? (float)bias_n[col] : 0.f;
#pragma unroll
            for (int r = 0; r < 4; ++r) {
                int row = m0 + wr + mt * 16 + lg * 4 + r;
                float vv = acc[mt][nt][r] + bn;
                if (bias_m) vv += (float)bias_m[row];
                if (relu) vv = fmaxf(vv, 0.f);
                if (swz == 1 && col >= 1024) {
                    swz_store(swzbuf, (col - 1024) >> 6, row >> 6, row & 63, (col - 1024) & 63, vv);
                } else if (swz == 2) {
                    swz_store(swzbuf, row >> 6, col >> 6, row & 63, col & 63, vv);
                } else {
                    size_t idx = (size_t)row * N + col;
                    if (res_mode) vv += rf32 ? ((const float*)res)[idx]
                                             : (float)(((const __bf16*)res)[idx]);
                    if (of32) ((float*)C)[idx] = vv;
                    else ((__bf16*)C)[idx] = (__bf16)vv;
                }
            }
        }
    }
}

// ---------------------------------------------------------------------------
// GEMM 128x64 (256 thr), BK=64: half the barriers, 16 MFMA per staging phase.
// LDS layout [row][64] with chunk-XOR swizzle (chunk ^= row&7) applied via the
// GLOBAL source address (linear global_load_lds dest) and on the ds_read side,
// keeping full-32-bank b128 reads. 24 KiB LDS.
// ---------------------------------------------------------------------------
__global__ __launch_bounds__(256) void gemm_n64(const __bf16* __restrict__ A, int lda,
                                                const __bf16* __restrict__ Bt, int ldb,
                                                const __bf16* __restrict__ bias_n,
                                                const __bf16* __restrict__ bias_m,
                                                const void* res, int res_mode,
                                                const float* flag,
                                                void* C, int out_pf,
                                                int M, int N, int K, int relu,
                                                __bf16* swzbuf, int swz) {
    __shared__ __bf16 As[128 * 64];
    __shared__ __bf16 Bs[64 * 64];
    const int tid = threadIdx.x;
    const int m0 = blockIdx.y * 128;
    const int n0 = blockIdx.x * 64;
    const int w = tid >> 6, lane = tid & 63;
    const int wr = (w >> 1) * 64, wc = (w & 1) * 32;
    const int lm = lane & 15, lg = lane >> 4;
    const int sw = lm & 7;
    const bool f32 = *flag > 0.5f;
    const bool rf32 = (res_mode == 2) && f32;
    const bool of32 = out_pf && f32;

    f32x4 acc[4][2] = {};
    for (int k0 = 0; k0 < K; k0 += 64) {
#pragma unroll
        for (int i = 0; i < 4; ++i) {
            int c = i * 256 + tid;
            int row = c >> 3, ch = c & 7;
            __builtin_amdgcn_global_load_lds(
                (const __attribute__((address_space(1))) void*)(A + (size_t)(m0 + row) * lda + k0 + ((ch ^ (row & 7)) << 3)),
                (__attribute__((address_space(3))) void*)(As + c * 8), 16, 0, 0);
        }
#pragma unroll
        for (int i = 0; i < 2; ++i) {
            int c = i * 256 + tid;
            int row = c >> 3, ch = c & 7;
            __builtin_amdgcn_global_load_lds(
                (const __attribute__((address_space(1))) void*)(Bt + (size_t)(n0 + row) * ldb + k0 + ((ch ^ (row & 7)) << 3)),
                (__attribute__((address_space(3))) void*)(Bs + c * 8), 16, 0, 0);
        }
        __syncthreads();
        bf16x8 a[4][2], b[2][2];
#pragma unroll
        for (int t = 0; t < 4; ++t)
#pragma unroll
            for (int h = 0; h < 2; ++h)
                a[t][h] = *(const bf16x8*)(As + (wr + t * 16 + lm) * 64 + ((((h << 2) | lg) ^ sw) << 3));
#pragma unroll
        for (int t = 0; t < 2; ++t)
#pragma unroll
            for (int h = 0; h < 2; ++h)
                b[t][h] = *(const bf16x8*)(Bs + (wc + t * 16 + lm) * 64 + ((((h << 2) | lg) ^ sw) << 3));
#pragma unroll
        for (int mt = 0; mt < 4; ++mt)
#pragma unroll
            for (int nt = 0; nt < 2; ++nt) {
                acc[mt][nt] = MFMA(a[mt][0], b[nt][0], acc[mt][nt]);
                acc[mt][nt] = MFMA(a[mt][1], b[nt][1], acc[mt][nt]);
            }
        __syncthreads();
    }
#pragma unroll
    for (int mt = 0; mt < 4; ++mt) {
#pragma unroll
        for (int nt = 0; nt < 2; ++nt) {
            int col = n0 + wc + nt * 16 + lm;
            float bn = bias_n ? (float)bias_n[col] : 0.f;
#pragma unroll
            for (int r = 0; r < 4; ++r) {
                int row = m0 + wr + mt * 16 + lg * 4 + r;
                float vv = acc[mt][nt][r] + bn;
                if (bias_m) vv += (float)bias_m[row];
                if (relu) vv = fmaxf(vv, 0.f);
                if (swz == 2) {
                    swz_store(swzbuf, row >> 6, col >> 6, row & 63, col & 63, vv);
                } else {
                    size_t idx = (size_t)row * N + col;
                    if (res_mode) vv += rf32 ? ((const float*)res)[idx]
                                             : (float)(((const __bf16*)res)[idx]);
                    if (of32) ((float*)C)[idx] = vv;
                    else ((__bf16*)C)[idx] = (__bf16)vv;
                }
            }
        }
    }
}

// ---------------------------------------------------------------------------
// Attention v7: K=32 PV via kv-permutation. P B-frags are register concats of
// the two pk4 outputs of adjacent 16-chunks; V A-frags read the SAME four sh4s
// per lane as the K=16 version, re-paired. PV+rowsum: 20 MFMAs/tile (was 48).
// ---------------------------------------------------------------------------
__global__ __launch_bounds__(256) void attn_ks2(const __bf16* __restrict__ Q, int ldq,
                                                const __bf16* __restrict__ Kswz,
                                                const __bf16* __restrict__ Vswz,
                                                __bf16* __restrict__ Opart,
                                                float* __restrict__ lpart) {
    constexpr int S = 4096;
    __shared__ __bf16 lds[2 * 8192];   // [buf][K tile 4096 | V tile 4096]
    const int h = blockIdx.y, z = blockIdx.z;
    const int q0 = blockIdx.x * 128;
    const int tid = threadIdx.x, w = tid >> 6, lane = tid & 63;
    const int lm = lane & 15, lg = lane >> 4;

    const __bf16* gK = Kswz + (((size_t)h * 64 + z * 32) << 12);
    const __bf16* gV = Vswz + (((size_t)h * 64 + z * 32) << 12);

    // Q B-frags (n=lm is q), pre-scaled by 0.125*log2e.
    bf16x8 qf[2][2];
#pragma unroll
    for (int qc = 0; qc < 2; ++qc) {
        const __bf16* qp = Q + (size_t)(q0 + w * 32 + qc * 16 + lm) * ldq + h * 64;
        qf[qc][0] = *(const bf16x8*)(qp + lg * 8);
        qf[qc][1] = *(const bf16x8*)(qp + 32 + lg * 8);
#pragma unroll
        for (int hh = 0; hh < 2; ++hh) {
            bf16x8 t = qf[qc][hh];
#pragma unroll
            for (int i = 0; i < 8; ++i) t[i] = (__bf16)((float)t[i] * 0.1803368801f);
            qf[qc][hh] = t;
        }
    }
    bf16x8 ones8;
#pragma unroll
    for (int i = 0; i < 8; ++i) ones8[i] = (__bf16)1.f;

    f32x4 o_[4][2] = {};
    f32x4 l_[2] = {};

    auto issue = [&](int t) {
        __bf16* dK = lds + (t & 1) * 8192;
        __bf16* dV = dK + 4096;
        const __bf16* sK = gK + ((size_t)t << 12);
        const __bf16* sV = gV + ((size_t)t << 12);
#pragma unroll
        for (int i = 0; i < 2; ++i) {
            int c = i * 256 + tid;
            __builtin_amdgcn_global_load_lds(
                (const __attribute__((address_space(1))) void*)(sK + c * 8),
                (__attribute__((address_space(3))) void*)(dK + c * 8), 16, 0, 0);
            __builtin_amdgcn_global_load_lds(
                (const __attribute__((address_space(1))) void*)(sV + c * 8),
                (__attribute__((address_space(3))) void*)(dV + c * 8), 16, 0, 0);
        }
    };
    issue(0);
    for (int t = 0; t < 32; ++t) {
        __syncthreads();                 // drains DMA for tile t; closes prev compute
        if (t < 31) issue(t + 1);        // in flight across this tile's compute
        const __bf16* Kt = lds + (t & 1) * 8192;
        const __bf16* Vt = Kt + 4096;

        P8 pb[2][2];
#pragma unroll
        for (int mt = 0; mt < 4; ++mt) {
            int rr = mt * 16 + lm;
            const __bf16* kr = Kt + rr * 64;
            bf16x8 kf0 = *(const bf16x8*)(kr + ((lg ^ (rr & 7)) << 3));
            bf16x8 kf1 = *(const bf16x8*)(kr + (((4 + lg) ^ (rr & 7)) << 3));
#pragma unroll
            for (int qc = 0; qc < 2; ++qc) {
                f32x4 s = (f32x4){0.f, 0.f, 0.f, 0.f};
                s = MFMA(kf0, qf[qc][0], s);
                s = MFMA(kf1, qf[qc][1], s);
                sh4 e = pk4(EXP2(s[0]), EXP2(s[1]), EXP2(s[2]), EXP2(s[3]));
                if (mt & 1) pb[mt >> 1][qc].p.hi = e;
                else        pb[mt >> 1][qc].p.lo = e;
            }
        }
#pragma unroll
        for (int mtd = 0; mtd < 4; ++mtd) {
            int rr = mtd * 16 + lm;
            const __bf16* vr = Vt + rr * 64;
#pragma unroll
            for (int cp = 0; cp < 2; ++cp) {
                int cbase = cp * 4 + (lg >> 1);
                P8 va;
                va.p.lo = *(const sh4*)(vr + ((cbase ^ (rr & 7)) << 3) + (lg & 1) * 4);
                va.p.hi = *(const sh4*)(vr + (((cbase + 2) ^ (rr & 7)) << 3) + (lg & 1) * 4);
                bf16x8 vab = __builtin_bit_cast(bf16x8, va.v);
                o_[mtd][0] = MFMA(vab, __builtin_bit_cast(bf16x8, pb[cp][0].v), o_[mtd][0]);
                o_[mtd][1] = MFMA(vab, __builtin_bit_cast(bf16x8, pb[cp][1].v), o_[mtd][1]);
            }
        }
#pragma unroll
        for (int cp = 0; cp < 2; ++cp) {
            l_[0] = MFMA(ones8, __builtin_bit_cast(bf16x8, pb[cp][0].v), l_[0]);
            l_[1] = MFMA(ones8, __builtin_bit_cast(bf16x8, pb[cp][1].v), l_[1]);
        }
    }

    // Unnormalized O^T -> lds[128][72] (packed 8B stores) -> coalesced store.
    __syncthreads();
#pragma unroll
    for (int qc = 0; qc < 2; ++qc) {
#pragma unroll
        for (int mtd = 0; mtd < 4; ++mtd) {
            sh4 ov = pk4(o_[mtd][qc][0], o_[mtd][qc][1], o_[mtd][qc][2], o_[mtd][qc][3]);
            *(sh4*)(lds + (w * 32 + qc * 16 + lm) * 72 + mtd * 16 + lg * 4) = ov;
        }
        if (lg == 0)
            lpart[(size_t)(h * 2 + z) * S + q0 + w * 32 + qc * 16 + lm] = l_[qc][0];
    }
    __syncthreads();
    __bf16* Ob = Opart + (((size_t)(h * 2 + z) * S + q0) << 6);
    int row = tid >> 1, co = (tid & 1) * 32;
#pragma unroll
    for (int b = 0; b < 4; ++b)
        *(uint4*)(Ob + row * 64 + co + b * 8) = *(const uint4*)(lds + row * 72 + co + b * 8);
}

__global__ __launch_bounds__(256) void attn_comb(const __bf16* __restrict__ Opart,
                                                 const float* __restrict__ lpart,
                                                 __bf16* __restrict__ ctx) {
    constexpr int S = 4096;
#pragma unroll
    for (int it = 0; it < 4; ++it) {
        int task = blockIdx.x * 1024 + it * 256 + threadIdx.x;  // (q, c8)
        int q = task >> 7, c8 = task & 127, h = c8 >> 3, d8 = (c8 & 7) * 8;
        const __bf16* p0 = Opart + (((size_t)(h * 2 + 0) * S + q) << 6) + d8;
        const __bf16* p1 = Opart + (((size_t)(h * 2 + 1) * S + q) << 6) + d8;
        float inv = 1.f / (lpart[(size_t)(h * 2 + 0) * S + q] + lpart[(size_t)(h * 2 + 1) * S + q]);
        bf16x8 a = *(const bf16x8*)p0, b = *(const bf16x8*)p1, o;
#pragma unroll
        for (int i = 0; i < 8; ++i) o[i] = (__bf16)(((float)a[i] + (float)b[i]) * inv);
        *(bf16x8*)(ctx + (size_t)q * 1024 + c8 * 8) = o;
    }
}

// ---------------------------------------------------------------------------
// r6 attention (padded-LDS, no split) — fallback path only. Same K=32 PV.
// ---------------------------------------------------------------------------
__global__ __launch_bounds__(256) void attn_v3(const __bf16* __restrict__ Q, int ldq,
                                               const __bf16* __restrict__ Kg, int ldk,
                                               const __bf16* __restrict__ VT,
                                               __bf16* __restrict__ ctx) {
    constexpr int S = 4096, D = 1024, LDT = 72;
    __shared__ __bf16 lds[128 * LDT];
    __bf16* Kt = lds;
    __bf16* Vt = lds + 64 * LDT;
    const int h = blockIdx.y;
    const int q0 = blockIdx.x * 128;
    const int tid = threadIdx.x, w = tid >> 6, lane = tid & 63;
    const int lm = lane & 15, lg = lane >> 4;
    bf16x8 qf[2][2];
#pragma unroll
    for (int qc = 0; qc < 2; ++qc) {
        const __bf16* qp = Q + (size_t)(q0 + w * 32 + qc * 16 + lm) * ldq + h * 64;
        qf[qc][0] = *(const bf16x8*)(qp + lg * 8);
        qf[qc][1] = *(const bf16x8*)(qp + 32 + lg * 8);
#pragma unroll
        for (int hh = 0; hh < 2; ++hh) {
            bf16x8 t = qf[qc][hh];
#pragma unroll
            for (int i = 0; i < 8; ++i) t[i] = (__bf16)((float)t[i] * 0.1803368801f);
            qf[qc][hh] = t;
        }
    }
    bf16x8 ones8;
#pragma unroll
    for (int i = 0; i < 8; ++i) ones8[i] = (__bf16)1.f;
    f32x4 o_[4][2] = {};
    f32x4 l_[2] = {};
    for (int kt = 0; kt < S / 64; ++kt) {
        __syncthreads();
#pragma unroll
        for (int i = 0; i < 2; ++i) {
            int c = i * 256 + tid;
            int rr = c >> 3, cc = (c & 7) * 8;
            *(uint4*)(Kt + rr * LDT + cc) =
                *(const uint4*)(Kg + (size_t)(kt * 64 + rr) * ldk + h * 64 + cc);
            *(uint4*)(Vt + rr * LDT + cc) =
                *(const uint4*)(VT + (size_t)(h * 64 + rr) * S + kt * 64 + cc);
        }
        __syncthreads();
        P8 pb[2][2];
#pragma unroll
        for (int mt = 0; mt < 4; ++mt) {
            bf16x8 kf0 = *(const bf16x8*)(Kt + (mt * 16 + lm) * LDT + lg * 8);
            bf16x8 kf1 = *(const bf16x8*)(Kt + (mt * 16 + lm) * LDT + 32 + lg * 8);
#pragma unroll
            for (int qc = 0; qc < 2; ++qc) {
                f32x4 s = (f32x4){0.f, 0.f, 0.f, 0.f};
                s = MFMA(kf0, qf[qc][0], s);
                s = MFMA(kf1, qf[qc][1], s);
                sh4 e = pk4(EXP2(s[0]), EXP2(s[1]), EXP2(s[2]), EXP2(s[3]));
                if (mt & 1) pb[mt >> 1][qc].p.hi = e;
                else        pb[mt >> 1][qc].p.lo = e;
            }
        }
#pragma unroll
        for (int mtd = 0; mtd < 4; ++mtd) {
            const __bf16* vrow = Vt + (mtd * 16 + lm) * LDT;
#pragma unroll
            for (int cp = 0; cp < 2; ++cp) {
                P8 va;
                va.p.lo = *(const sh4*)(vrow + cp * 32 + lg * 4);
                va.p.hi = *(const sh4*)(vrow + cp * 32 + 16 + lg * 4);
                bf16x8 vab = __builtin_bit_cast(bf16x8, va.v);
                o_[mtd][0] = MFMA(vab, __builtin_bit_cast(bf16x8, pb[cp][0].v), o_[mtd][0]);
                o_[mtd][1] = MFMA(vab, __builtin_bit_cast(bf16x8, pb[cp][1].v), o_[mtd][1]);
            }
        }
#pragma unroll
        for (int cp = 0; cp < 2; ++cp) {
            l_[0] = MFMA(ones8, __builtin_bit_cast(bf16x8, pb[cp][0].v), l_[0]);
            l_[1] = MFMA(ones8, __builtin_bit_cast(bf16x8, pb[cp][1].v), l_[1]);
        }
    }
    __syncthreads();
    float inv[2] = {1.f / l_[0][0], 1.f / l_[1][0]};
#pragma unroll
    for (int qc = 0; qc < 2; ++qc)
#pragma unroll
        for (int mtd = 0; mtd < 4; ++mtd)
#pragma unroll
            for (int r = 0; r < 4; ++r)
                lds[(w * 32 + qc * 16 + lm) * LDT + mtd * 16 + lg * 4 + r] =
                    (__bf16)(o_[mtd][qc][r] * inv[qc]);
    __syncthreads();
    int row = tid >> 1, cb = (tid & 1) * 32;
#pragma unroll
    for (int b = 0; b < 4; ++b)
        *(uint4*)(ctx + (size_t)(q0 + row) * D + h * 64 + cb + b * 8) =
            *(const uint4*)(lds + row * LDT + cb + b * 8);
}

// ---------------------------------------------------------------------------
extern "C" void kernel_launch(void* const* d_in, const int* in_sizes, int n_in,
                              void* d_out, int out_size, void* d_ws, size_t ws_size,
                              hipStream_t stream) {
    const void* x    = d_in[0];
    const void* Wq   = d_in[1];
    const void* bq   = d_in[2];
    const void* Wk   = d_in[3];
    const void* bk   = d_in[4];
    const void* Wv   = d_in[5];
    const void* bv   = d_in[6];
    const void* Wo   = d_in[7];
    const void* bo   = d_in[8];
    const void* ln1a = d_in[9];
    const void* ln1b = d_in[10];
    const void* W1   = d_in[11];
    const void* b1   = d_in[12];
    const void* W2   = d_in[13];
    const void* b2   = d_in[14];
    const void* ln2a = d_in[15];
    const void* ln2b = d_in[16];

    constexpr size_t M1 = 1u << 20;
    __bf16* ws = (__bf16*)d_ws;
    float* flagF = (float*)ws;
    __bf16* bmir = ws;
    dim3 tb(32, 8);
    const bool big = ws_size >= (size_t)(32.25 * 2 * M1) + 4096;

    prep_k<<<1, 256, 0, stream>>>(Wq, flagF, bq, bk, bv, bo, b1, b2,
                                  ln1a, ln1b, ln2a, ln2b, bmir);

    if (big) {
        // peak 32.25M elems = 64.5 MB
        __bf16* WqT = ws + M1 / 4;
        __bf16* WkT = WqT + M1;
        __bf16* WvT = ws + 2 * M1 + M1 / 4;
        __bf16* WoT = ws + 3 * M1 + M1 / 4;
        __bf16* W2T = ws + M1 / 4;
        float* lpart = (float*)(ws + M1 / 4);
        __bf16* hb  = ws + 4 * M1 + M1 / 4;
        __bf16* h2  = hb;
        __bf16* QKb = ws + 8 * M1 + M1 / 4;
        __bf16* x2  = QKb;
        __bf16* W1T = ws + 12 * M1 + M1 / 4;
        __bf16* Kswz = ws + 16 * M1 + M1 / 4;
        __bf16* ctx  = Kswz;
        __bf16* Vswz = ws + 20 * M1 + M1 / 4;
        __bf16* Opart = ws + 24 * M1 + M1 / 4;
        __bf16* f1  = ws + 16 * M1 + M1 / 4;

        transpose4_cvt<<<dim3(32, 32, 4), tb, 0, stream>>>(Wq, Wk, Wv, Wo,
                                                           WqT, WkT, WvT, WoT, flagF);
        layernorm_k<<<1024, 256, 0, stream>>>(x, 1, flagF, hb, bmir + 10240, bmir + 10241);
        gemm_bt<<<dim3(16, 32), 256, 0, stream>>>(hb, 1024, WqT, 1024, bmir + 1024, nullptr,
                                                  nullptr, 0, flagF, QKb, 0, 4096, 2048, 1024, 0,
                                                  Kswz, 1);
        gemm_n64<<<dim3(64, 8), 256, 0, stream>>>(WvT, 1024, hb, 1024, nullptr, bmir + 3072,
                                                  nullptr, 0, flagF, nullptr, 0, 1024, 4096, 1024, 0,
                                                  Vswz, 2);
        attn_ks2<<<dim3(32, 16, 2), 256, 0, stream>>>(QKb, 2048, Kswz, Vswz, Opart, lpart);
        attn_comb<<<512, 256, 0, stream>>>(Opart, lpart, ctx);
        transpose_cvt<<<dim3(128, 32), tb, 0, stream>>>(W1, W1T, 1024, 4096, flagF);
        gemm_n64<<<dim3(16, 32), 256, 0, stream>>>(ctx, 1024, WoT, 1024, bmir + 4096, nullptr,
                                                   x, 2, flagF, x2, 0, 4096, 1024, 1024, 0,
                                                   nullptr, 0);
        transpose_cvt<<<dim3(32, 128), tb, 0, stream>>>(W2, W2T, 4096, 1024, flagF);
        layernorm_k<<<1024, 256, 0, stream>>>(x2, 0, flagF, h2, bmir + 10242, bmir + 10243);
        gemm_bt<<<dim3(32, 32), 256, 0, stream>>>(h2, 1024, W1T, 1024, bmir + 5120, nullptr,
                                                  nullptr, 0, flagF, f1, 0, 4096, 4096, 1024, 1,
                                                  nullptr, 0);
        gemm_n64<<<dim3(16, 32), 256, 0, stream>>>(f1, 4096, W2T, 4096, bmir + 9216, nullptr,
                                                   x2, 1, flagF, d_out, 1, 4096, 1024, 4096, 0,
                                                   nullptr, 0);
    } else {
        // chunked fallback (r6), peak 46.5 MB
        constexpr size_t Qn = 1u << 18;
        __bf16* WqT = ws + Qn;
        __bf16* WoT = WqT;
        __bf16* WkT = ws + 5 * Qn;
        __bf16* WvT = ws + 9 * Qn;
        __bf16* hb  = ws + 13 * Qn;
        __bf16* f1q = hb;
        __bf16* ctx = ws + 29 * Qn;
        __bf16* W2T = ctx;
        __bf16* QKb = ws + 45 * Qn;
        __bf16* x2  = QKb;
        __bf16* Kb  = ws + 61 * Qn;
        __bf16* h2  = Kb;
        __bf16* VTb = ws + 77 * Qn;
        __bf16* W1T = VTb;
        transpose_cvt<<<dim3(32, 32), tb, 0, stream>>>(Wq, WqT, 1024, 1024, flagF);
        transpose_cvt<<<dim3(32, 32), tb, 0, stream>>>(Wk, WkT, 1024, 1024, flagF);
        transpose_cvt<<<dim3(32, 32), tb, 0, stream>>>(Wv, WvT, 1024, 1024, flagF);
        layernorm_k<<<1024, 256, 0, stream>>>(x, 1, flagF, hb, bmir + 10240, bmir + 10241);
        gemm_bt<<<dim3(8, 32), 256, 0, stream>>>(hb, 1024, WqT, 1024, bmir + 1024, nullptr,
                                                 nullptr, 0, flagF, QKb, 0, 4096, 1024, 1024, 0,
                                                 nullptr, 0);
        gemm_bt<<<dim3(8, 32), 256, 0, stream>>>(hb, 1024, WkT, 1024, bmir + 2048, nullptr,
                                                 nullptr, 0, flagF, Kb, 0, 4096, 1024, 1024, 0,
                                                 nullptr, 0);
        gemm_n64<<<dim3(64, 8), 256, 0, stream>>>(WvT, 1024, hb, 1024, nullptr, bmir + 3072,
                                                  nullptr, 0, flagF, VTb, 0, 1024, 4096, 1024, 0,
                                                  nullptr, 0);
        attn_v3<<<dim3(32, 16), 256, 0, stream>>>(QKb, 1024, Kb, 1024, VTb, ctx);
        transpose_cvt<<<dim3(32, 32), tb, 0, stream>>>(Wo, WoT, 1024, 1024, flagF);
        gemm_n64<<<dim3(16, 32), 256, 0, stream>>>(ctx, 1024, WoT, 1024, bmir + 4096, nullptr,
                                                   x, 2, flagF, x2, 0, 4096, 1024, 1024, 0,
                                                   nullptr, 0);
        layernorm_k<<<1024, 256, 0, stream>>>(x2, 0, flagF, h2, bmir + 10242, bmir + 10243);
        transpose_cvt<<<dim3(128, 32), tb, 0, stream>>>(W1, W1T, 1024, 4096, flagF);
        transpose_cvt<<<dim3(32, 128), tb, 0, stream>>>(W2, W2T, 4096, 1024, flagF);
        for (int ck = 0; ck < 2; ++ck) {
            gemm_bt<<<dim3(16, 32), 256, 0, stream>>>(h2, 1024, W1T + (size_t)ck * 2048 * 1024,
                                                      1024, bmir + 5120 + ck * 2048, nullptr,
                                                      nullptr, 0, flagF, f1q, 0, 4096, 2048, 1024, 1,
                                                      nullptr, 0);
            gemm_n64<<<dim3(16, 32), 256, 0, stream>>>(f1q, 2048, W2T + ck * 2048, 4096,
                                                       ck == 0 ? bmir + 9216 : nullptr, nullptr,
                                                       x2, 1, flagF, ck == 1 ? d_out : (void*)x2,
                                                       ck == 1 ? 1 : 0, 4096, 1024, 2048, 0,
                                                       nullptr, 0);
        }
    }
}

// Round 3
// 480.179 us; speedup vs baseline: 1.1202x; 1.0166x over previous
//
#include <hip/hip_runtime.h>
#include <hip/hip_bf16.h>

typedef __attribute__((ext_vector_type(8))) __bf16 bf16x8;
typedef __attribute__((ext_vector_type(4))) float f32x4;
typedef __attribute__((ext_vector_type(4))) short sh4;
typedef __attribute__((ext_vector_type(8))) short sh8;

#define MFMA(a, b, c) __builtin_amdgcn_mfma_f32_16x16x32_bf16(a, b, c, 0, 0, 0)

#if __has_builtin(__builtin_amdgcn_exp2f)
#define EXP2(x) __builtin_amdgcn_exp2f(x)
#else
#define EXP2(x) exp2f(x)
#endif

// K=32 B-frag / V-frag pairing: slot s = lg*8 + c*4 + r <-> kv-row c*16 + lg*4 + r.
// (kv is a contraction index; P and V use the same permutation, so this is exact.)
union P8 { struct { sh4 lo, hi; } p; sh8 v; };

// Packed f32->bf16 (v_cvt_pk_bf16_f32): 4 floats -> sh4 in 2 insts.
__device__ __forceinline__ sh4 pk4(float a, float b, float c, float d) {
    __hip_bfloat162 lo = __float22bfloat162_rn(float2{a, b});
    __hip_bfloat162 hi = __float22bfloat162_rn(float2{c, d});
    union { struct { __hip_bfloat162 lo, hi; } p; sh4 s; } u;
    u.p.lo = lo; u.p.hi = hi;
    return u.s;
}

__device__ __forceinline__ float ldany(const void* p, size_t i, bool f32) {
    return f32 ? ((const float*)p)[i] : (float)(((const __bf16*)p)[i]);
}

// ---------------------------------------------------------------------------
// Merged detect + small-conversions (one launch). offsets: bq 1024, bk 2048,
// bv 3072, bo 4096, b1 5120(4096), b2 9216, ln1a 10240..ln2b 10243.
__global__ void prep_k(const void* wq, float* flag,
                       const void* bq, const void* bk, const void* bv, const void* bo,
                       const void* b1, const void* b2,
                       const void* l1a, const void* l1b, const void* l2a, const void* l2b,
                       __bf16* dst) {
    __shared__ float red[256];
    __shared__ float fls;
    int tid = threadIdx.x;
    const __bf16* p = (const __bf16*)wq;
    float mx = 0.f;
    for (int i = tid; i < 1024; i += 256) {
        float v = (float)p[i];
        if (v != v) mx = 2.f;
        v = fabsf(v);
        if (v > mx) mx = v;
    }
    red[tid] = mx;
    __syncthreads();
    for (int s = 128; s > 0; s >>= 1) {
        if (tid < s) red[tid] = fmaxf(red[tid], red[tid + s]);
        __syncthreads();
    }
    if (tid == 0) { fls = (red[0] > 1.0f) ? 1.f : 0.f; *flag = fls; }
    __syncthreads();
    bool f32 = fls > 0.5f;
    const void* srcs[10] = {bq, bk, bv, bo, b1, b2, l1a, l1b, l2a, l2b};
    const int offs[10] = {1024, 2048, 3072, 4096, 5120, 9216, 10240, 10241, 10242, 10243};
    const int ns[10]   = {1024, 1024, 1024, 1024, 4096, 1024, 1, 1, 1, 1};
    for (int t = 0; t < 10; ++t)
        for (int j = tid; j < ns[t]; j += blockDim.x)
            dst[offs[t] + j] = (__bf16)ldany(srcs[t], j, f32);
}

// ---------------------------------------------------------------------------
__device__ __forceinline__ void tr_body(const void* in, __bf16* out, int R, int C, bool f32,
                                        int bx, int by, int x, int y) {
    __shared__ __bf16 t[32][33];
    for (int i = 0; i < 32; i += 8)
        t[y + i][x] = (__bf16)ldany(in, (size_t)(by + y + i) * C + bx + x, f32);
    __syncthreads();
    for (int i = 0; i < 32; i += 8)
        out[(size_t)(bx + y + i) * R + by + x] = t[x][y + i];
}

__global__ void transpose_cvt(const void* in, __bf16* out, int R, int C, const float* flag) {
    tr_body(in, out, R, C, *flag > 0.5f, blockIdx.x * 32, blockIdx.y * 32,
            threadIdx.x, threadIdx.y);
}

__global__ void transpose4_cvt(const void* i0, const void* i1, const void* i2, const void* i3,
                               __bf16* o0, __bf16* o1, __bf16* o2, __bf16* o3,
                               const float* flag) {
    const void* in = blockIdx.z == 0 ? i0 : blockIdx.z == 1 ? i1 : blockIdx.z == 2 ? i2 : i3;
    __bf16* out = blockIdx.z == 0 ? o0 : blockIdx.z == 1 ? o1 : blockIdx.z == 2 ? o2 : o3;
    tr_body(in, out, 1024, 1024, *flag > 0.5f, blockIdx.x * 32, blockIdx.y * 32,
            threadIdx.x, threadIdx.y);
}

// ---------------------------------------------------------------------------
__global__ __launch_bounds__(256) void layernorm_k(const void* x, int xmode, const float* flag,
                                                   __bf16* out,
                                                   const __bf16* alpha, const __bf16* beta) {
    int row = blockIdx.x * 4 + (threadIdx.x >> 6);
    int lane = threadIdx.x & 63;
    bool f32 = xmode && (*flag > 0.5f);
    float v[16];
    if (f32) {
        const float4* xr = (const float4*)((const float*)x + (size_t)row * 1024 + lane * 16);
#pragma unroll
        for (int q = 0; q < 4; ++q) {
            float4 r = xr[q];
            v[q * 4 + 0] = r.x; v[q * 4 + 1] = r.y; v[q * 4 + 2] = r.z; v[q * 4 + 3] = r.w;
        }
    } else {
        const __bf16* xr = (const __bf16*)x + (size_t)row * 1024 + lane * 16;
        bf16x8 h0 = *(const bf16x8*)xr;
        bf16x8 h1 = *(const bf16x8*)(xr + 8);
#pragma unroll
        for (int i = 0; i < 8; ++i) { v[i] = (float)h0[i]; v[8 + i] = (float)h1[i]; }
    }
    float s = 0.f, ss = 0.f;
#pragma unroll
    for (int i = 0; i < 16; ++i) { s += v[i]; ss += v[i] * v[i]; }
#pragma unroll
    for (int o = 1; o < 64; o <<= 1) { s += __shfl_xor(s, o); ss += __shfl_xor(ss, o); }
    float mu = s * (1.f / 1024.f);
    float var = (ss - 1024.f * mu * mu) * (1.f / 1023.f);
    float inv = 1.f / (sqrtf(var) + 1e-6f);
    float al = (float)alpha[0], be = (float)beta[0];
    bf16x8 o0, o1;
#pragma unroll
    for (int i = 0; i < 8; ++i) {
        o0[i] = (__bf16)((v[i] - mu) * inv * al + be);
        o1[i] = (__bf16)((v[8 + i] - mu) * inv * al + be);
    }
    __bf16* orow = out + (size_t)row * 1024;
    *(bf16x8*)(orow + lane * 16) = o0;
    *(bf16x8*)(orow + lane * 16 + 8) = o1;
}

// Swizzled-tile store helpers: 64x64 tiles, chunk (8 halves) XOR'd by row&7.
__device__ __forceinline__ void swz_store(__bf16* buf, int hh, int ktt, int rr2, int cc2,
                                          float v) {
    size_t off = (((size_t)hh * 64 + ktt) << 12) + rr2 * 64 +
                 (((cc2 >> 3) ^ (rr2 & 7)) << 3) + (cc2 & 7);
    buf[off] = (__bf16)v;
}

// ---------------------------------------------------------------------------
// GEMM 128x128 (256 thr), double-buffered LDS: stage k+1 before computing k,
// single __syncthreads per iter AFTER compute -> HBM/L3 latency hides under
// the 16-MFMA phase (short-K shapes here are latency-bound, not BW-bound).
// swz: 0 none; 1 = cols>=1024 are K -> swzbuf.
// ---------------------------------------------------------------------------
__global__ __launch_bounds__(256) void gemm_bt(const __bf16* __restrict__ A, int lda,
                                               const __bf16* __restrict__ Bt, int ldb,
                                               const __bf16* __restrict__ bias_n,
                                               const __bf16* __restrict__ bias_m,
                                               const void* res, int res_mode,
                                               const float* flag,
                                               void* C, int out_pf,
                                               int M, int N, int K, int relu,
                                               __bf16* swzbuf, int swz) {
    __shared__ __bf16 As[2][128 * 32];
    __shared__ __bf16 Bs[2][128 * 32];
    const int tid = threadIdx.x;
    const int m0 = blockIdx.y * 128;
    const int n0 = blockIdx.x * 128;
    const int w = tid >> 6, lane = tid & 63;
    const int wr = (w >> 1) * 64, wc = (w & 1) * 64;
    const int lm = lane & 15, lg = lane >> 4;
    const bool f32 = *flag > 0.5f;
    const bool rf32 = (res_mode == 2) && f32;
    const bool of32 = out_pf && f32;

    auto stage = [&](int buf, int k0) {
#pragma unroll
        for (int i = 0; i < 2; ++i) {
            int c = i * 256 + tid;
            int row = c >> 2, kk = (c & 3) * 8;
            __builtin_amdgcn_global_load_lds(
                (const __attribute__((address_space(1))) void*)(A + (size_t)(m0 + row) * lda + k0 + kk),
                (__attribute__((address_space(3))) void*)(As[buf] + c * 8), 16, 0, 0);
            __builtin_amdgcn_global_load_lds(
                (const __attribute__((address_space(1))) void*)(Bt + (size_t)(n0 + row) * ldb + k0 + kk),
                (__attribute__((address_space(3))) void*)(Bs[buf] + c * 8), 16, 0, 0);
        }
    };

    f32x4 acc[4][4] = {};
    stage(0, 0);
    __syncthreads();
    int cur = 0;
    for (int k0 = 0; k0 < K; k0 += 32) {
        if (k0 + 32 < K) stage(cur ^ 1, k0 + 32);
        bf16x8 a[4], b[4];
#pragma unroll
        for (int t = 0; t < 4; ++t)
            a[t] = *(const bf16x8*)(As[cur] + (wr + t * 16 + lm) * 32 + lg * 8);
#pragma unroll
        for (int t = 0; t < 4; ++t)
            b[t] = *(const bf16x8*)(Bs[cur] + (wc + t * 16 + lm) * 32 + lg * 8);
#pragma unroll
        for (int mt = 0; mt < 4; ++mt)
#pragma unroll
            for (int nt = 0; nt < 4; ++nt)
                acc[mt][nt] = MFMA(a[mt], b[nt], acc[mt][nt]);
        __syncthreads();   // drains vmcnt: next-tile loads had the whole MFMA phase
        cur ^= 1;
    }
#pragma unroll
    for (int mt = 0; mt < 4; ++mt) {
#pragma unroll
        for (int nt = 0; nt < 4; ++nt) {
            int col = n0 + wc + nt * 16 + lm;
            float bn = bias_n ? (float)bias_n[col] : 0.f;
#pragma unroll
            for (int r = 0; r < 4; ++r) {
                int row = m0 + wr + mt * 16 + lg * 4 + r;
                float vv = acc[mt][nt][r] + bn;
                if (bias_m) vv += (float)bias_m[row];
                if (relu) vv = fmaxf(vv, 0.f);
                if (swz == 1 && col >= 1024) {
                    swz_store(swzbuf, (col - 1024) >> 6, row >> 6, row & 63, (col - 1024) & 63, vv);
                } else if (swz == 2) {
                    swz_store(swzbuf, row >> 6, col >> 6, row & 63, col & 63, vv);
                } else {
                    size_t idx = (size_t)row * N + col;
                    if (res_mode) vv += rf32 ? ((const float*)res)[idx]
                                             : (float)(((const __bf16*)res)[idx]);
                    if (of32) ((float*)C)[idx] = vv;
                    else ((__bf16*)C)[idx] = (__bf16)vv;
                }
            }
        }
    }
}

// ---------------------------------------------------------------------------
// GEMM 128x64 (256 thr), BK=64, double-buffered (48 KiB LDS, 3 blocks/CU).
// Chunk-XOR swizzle applied via pre-swizzled GLOBAL source (linear LDS dest)
// and on the ds_read side. Single barrier per K-step, drain after compute.
// ---------------------------------------------------------------------------
__global__ __launch_bounds__(256) void gemm_n64(const __bf16* __restrict__ A, int lda,
                                                const __bf16* __restrict__ Bt, int ldb,
                                                const __bf16* __restrict__ bias_n,
                                                const __bf16* __restrict__ bias_m,
                                                const void* res, int res_mode,
                                                const float* flag,
                                                void* C, int out_pf,
                                                int M, int N, int K, int relu,
                                                __bf16* swzbuf, int swz) {
    __shared__ __bf16 As[2][128 * 64];
    __shared__ __bf16 Bs[2][64 * 64];
    const int tid = threadIdx.x;
    const int m0 = blockIdx.y * 128;
    const int n0 = blockIdx.x * 64;
    const int w = tid >> 6, lane = tid & 63;
    const int wr = (w >> 1) * 64, wc = (w & 1) * 32;
    const int lm = lane & 15, lg = lane >> 4;
    const int sw = lm & 7;
    const bool f32 = *flag > 0.5f;
    const bool rf32 = (res_mode == 2) && f32;
    const bool of32 = out_pf && f32;

    auto stage = [&](int buf, int k0) {
#pragma unroll
        for (int i = 0; i < 4; ++i) {
            int c = i * 256 + tid;
            int row = c >> 3, ch = c & 7;
            __builtin_amdgcn_global_load_lds(
                (const __attribute__((address_space(1))) void*)(A + (size_t)(m0 + row) * lda + k0 + ((ch ^ (row & 7)) << 3)),
                (__attribute__((address_space(3))) void*)(As[buf] + c * 8), 16, 0, 0);
        }
#pragma unroll
        for (int i = 0; i < 2; ++i) {
            int c = i * 256 + tid;
            int row = c >> 3, ch = c & 7;
            __builtin_amdgcn_global_load_lds(
                (const __attribute__((address_space(1))) void*)(Bt + (size_t)(n0 + row) * ldb + k0 + ((ch ^ (row & 7)) << 3)),
                (__attribute__((address_space(3))) void*)(Bs[buf] + c * 8), 16, 0, 0);
        }
    };

    f32x4 acc[4][2] = {};
    stage(0, 0);
    __syncthreads();
    int cur = 0;
    for (int k0 = 0; k0 < K; k0 += 64) {
        if (k0 + 64 < K) stage(cur ^ 1, k0 + 64);
        bf16x8 a[4][2], b[2][2];
#pragma unroll
        for (int t = 0; t < 4; ++t)
#pragma unroll
            for (int h = 0; h < 2; ++h)
                a[t][h] = *(const bf16x8*)(As[cur] + (wr + t * 16 + lm) * 64 + ((((h << 2) | lg) ^ sw) << 3));
#pragma unroll
        for (int t = 0; t < 2; ++t)
#pragma unroll
            for (int h = 0; h < 2; ++h)
                b[t][h] = *(const bf16x8*)(Bs[cur] + (wc + t * 16 + lm) * 64 + ((((h << 2) | lg) ^ sw) << 3));
#pragma unroll
        for (int mt = 0; mt < 4; ++mt)
#pragma unroll
            for (int nt = 0; nt < 2; ++nt) {
                acc[mt][nt] = MFMA(a[mt][0], b[nt][0], acc[mt][nt]);
                acc[mt][nt] = MFMA(a[mt][1], b[nt][1], acc[mt][nt]);
            }
        __syncthreads();   // drain after compute: k+1 loads overlapped the MFMAs
        cur ^= 1;
    }
#pragma unroll
    for (int mt = 0; mt < 4; ++mt) {
#pragma unroll
        for (int nt = 0; nt < 2; ++nt) {
            int col = n0 + wc + nt * 16 + lm;
            float bn = bias_n ? (float)bias_n[col] : 0.f;
#pragma unroll
            for (int r = 0; r < 4; ++r) {
                int row = m0 + wr + mt * 16 + lg * 4 + r;
                float vv = acc[mt][nt][r] + bn;
                if (bias_m) vv += (float)bias_m[row];
                if (relu) vv = fmaxf(vv, 0.f);
                if (swz == 2) {
                    swz_store(swzbuf, row >> 6, col >> 6, row & 63, col & 63, vv);
                } else {
                    size_t idx = (size_t)row * N + col;
                    if (res_mode) vv += rf32 ? ((const float*)res)[idx]
                                             : (float)(((const __bf16*)res)[idx]);
                    if (of32) ((float*)C)[idx] = vv;
                    else ((__bf16*)C)[idx] = (__bf16)vv;
                }
            }
        }
    }
}

// ---------------------------------------------------------------------------
// Attention v7: K=32 PV via kv-permutation. P B-frags are register concats of
// the two pk4 outputs of adjacent 16-chunks; V A-frags read the SAME four sh4s
// per lane as the K=16 version, re-paired. PV+rowsum: 20 MFMAs/tile (was 48).
// ---------------------------------------------------------------------------
__global__ __launch_bounds__(256) void attn_ks2(const __bf16* __restrict__ Q, int ldq,
                                                const __bf16* __restrict__ Kswz,
                                                const __bf16* __restrict__ Vswz,
                                                __bf16* __restrict__ Opart,
                                                float* __restrict__ lpart) {
    constexpr int S = 4096;
    __shared__ __bf16 lds[2 * 8192];   // [buf][K tile 4096 | V tile 4096]
    const int h = blockIdx.y, z = blockIdx.z;
    const int q0 = blockIdx.x * 128;
    const int tid = threadIdx.x, w = tid >> 6, lane = tid & 63;
    const int lm = lane & 15, lg = lane >> 4;

    const __bf16* gK = Kswz + (((size_t)h * 64 + z * 32) << 12);
    const __bf16* gV = Vswz + (((size_t)h * 64 + z * 32) << 12);

    // Q B-frags (n=lm is q), pre-scaled by 0.125*log2e.
    bf16x8 qf[2][2];
#pragma unroll
    for (int qc = 0; qc < 2; ++qc) {
        const __bf16* qp = Q + (size_t)(q0 + w * 32 + qc * 16 + lm) * ldq + h * 64;
        qf[qc][0] = *(const bf16x8*)(qp + lg * 8);
        qf[qc][1] = *(const bf16x8*)(qp + 32 + lg * 8);
#pragma unroll
        for (int hh = 0; hh < 2; ++hh) {
            bf16x8 t = qf[qc][hh];
#pragma unroll
            for (int i = 0; i < 8; ++i) t[i] = (__bf16)((float)t[i] * 0.1803368801f);
            qf[qc][hh] = t;
        }
    }
    bf16x8 ones8;
#pragma unroll
    for (int i = 0; i < 8; ++i) ones8[i] = (__bf16)1.f;

    f32x4 o_[4][2] = {};
    f32x4 l_[2] = {};

    auto issue = [&](int t) {
        __bf16* dK = lds + (t & 1) * 8192;
        __bf16* dV = dK + 4096;
        const __bf16* sK = gK + ((size_t)t << 12);
        const __bf16* sV = gV + ((size_t)t << 12);
#pragma unroll
        for (int i = 0; i < 2; ++i) {
            int c = i * 256 + tid;
            __builtin_amdgcn_global_load_lds(
                (const __attribute__((address_space(1))) void*)(sK + c * 8),
                (__attribute__((address_space(3))) void*)(dK + c * 8), 16, 0, 0);
            __builtin_amdgcn_global_load_lds(
                (const __attribute__((address_space(1))) void*)(sV + c * 8),
                (__attribute__((address_space(3))) void*)(dV + c * 8), 16, 0, 0);
        }
    };
    issue(0);
    for (int t = 0; t < 32; ++t) {
        __syncthreads();                 // drains DMA for tile t; closes prev compute
        if (t < 31) issue(t + 1);        // in flight across this tile's compute
        const __bf16* Kt = lds + (t & 1) * 8192;
        const __bf16* Vt = Kt + 4096;

        P8 pb[2][2];
#pragma unroll
        for (int mt = 0; mt < 4; ++mt) {
            int rr = mt * 16 + lm;
            const __bf16* kr = Kt + rr * 64;
            bf16x8 kf0 = *(const bf16x8*)(kr + ((lg ^ (rr & 7)) << 3));
            bf16x8 kf1 = *(const bf16x8*)(kr + (((4 + lg) ^ (rr & 7)) << 3));
#pragma unroll
            for (int qc = 0; qc < 2; ++qc) {
                f32x4 s = (f32x4){0.f, 0.f, 0.f, 0.f};
                s = MFMA(kf0, qf[qc][0], s);
                s = MFMA(kf1, qf[qc][1], s);
                sh4 e = pk4(EXP2(s[0]), EXP2(s[1]), EXP2(s[2]), EXP2(s[3]));
                if (mt & 1) pb[mt >> 1][qc].p.hi = e;
                else        pb[mt >> 1][qc].p.lo = e;
            }
        }
#pragma unroll
        for (int mtd = 0; mtd < 4; ++mtd) {
            int rr = mtd * 16 + lm;
            const __bf16* vr = Vt + rr * 64;
#pragma unroll
            for (int cp = 0; cp < 2; ++cp) {
                int cbase = cp * 4 + (lg >> 1);
                P8 va;
                va.p.lo = *(const sh4*)(vr + ((cbase ^ (rr & 7)) << 3) + (lg & 1) * 4);
                va.p.hi = *(const sh4*)(vr + (((cbase + 2) ^ (rr & 7)) << 3) + (lg & 1) * 4);
                bf16x8 vab = __builtin_bit_cast(bf16x8, va.v);
                o_[mtd][0] = MFMA(vab, __builtin_bit_cast(bf16x8, pb[cp][0].v), o_[mtd][0]);
                o_[mtd][1] = MFMA(vab, __builtin_bit_cast(bf16x8, pb[cp][1].v), o_[mtd][1]);
            }
        }
#pragma unroll
        for (int cp = 0; cp < 2; ++cp) {
            l_[0] = MFMA(ones8, __builtin_bit_cast(bf16x8, pb[cp][0].v), l_[0]);
            l_[1] = MFMA(ones8, __builtin_bit_cast(bf16x8, pb[cp][1].v), l_[1]);
        }
    }

    // Unnormalized O^T -> lds[128][72] (packed 8B stores) -> coalesced store.
    __syncthreads();
#pragma unroll
    for (int qc = 0; qc < 2; ++qc) {
#pragma unroll
        for (int mtd = 0; mtd < 4; ++mtd) {
            sh4 ov = pk4(o_[mtd][qc][0], o_[mtd][qc][1], o_[mtd][qc][2], o_[mtd][qc][3]);
            *(sh4*)(lds + (w * 32 + qc * 16 + lm) * 72 + mtd * 16 + lg * 4) = ov;
        }
        if (lg == 0)
            lpart[(size_t)(h * 2 + z) * S + q0 + w * 32 + qc * 16 + lm] = l_[qc][0];
    }
    __syncthreads();
    __bf16* Ob = Opart + (((size_t)(h * 2 + z) * S + q0) << 6);
    int row = tid >> 1, co = (tid & 1) * 32;
#pragma unroll
    for (int b = 0; b < 4; ++b)
        *(uint4*)(Ob + row * 64 + co + b * 8) = *(const uint4*)(lds + row * 72 + co + b * 8);
}

__global__ __launch_bounds__(256) void attn_comb(const __bf16* __restrict__ Opart,
                                                 const float* __restrict__ lpart,
                                                 __bf16* __restrict__ ctx) {
    constexpr int S = 4096;
#pragma unroll
    for (int it = 0; it < 4; ++it) {
        int task = blockIdx.x * 1024 + it * 256 + threadIdx.x;  // (q, c8)
        int q = task >> 7, c8 = task & 127, h = c8 >> 3, d8 = (c8 & 7) * 8;
        const __bf16* p0 = Opart + (((size_t)(h * 2 + 0) * S + q) << 6) + d8;
        const __bf16* p1 = Opart + (((size_t)(h * 2 + 1) * S + q) << 6) + d8;
        float inv = 1.f / (lpart[(size_t)(h * 2 + 0) * S + q] + lpart[(size_t)(h * 2 + 1) * S + q]);
        bf16x8 a = *(const bf16x8*)p0, b = *(const bf16x8*)p1, o;
#pragma unroll
        for (int i = 0; i < 8; ++i) o[i] = (__bf16)(((float)a[i] + (float)b[i]) * inv);
        *(bf16x8*)(ctx + (size_t)q * 1024 + c8 * 8) = o;
    }
}

// ---------------------------------------------------------------------------
// r6 attention (padded-LDS, no split) — fallback path only. Same K=32 PV.
// ---------------------------------------------------------------------------
__global__ __launch_bounds__(256) void attn_v3(const __bf16* __restrict__ Q, int ldq,
                                               const __bf16* __restrict__ Kg, int ldk,
                                               const __bf16* __restrict__ VT,
                                               __bf16* __restrict__ ctx) {
    constexpr int S = 4096, D = 1024, LDT = 72;
    __shared__ __bf16 lds[128 * LDT];
    __bf16* Kt = lds;
    __bf16* Vt = lds + 64 * LDT;
    const int h = blockIdx.y;
    const int q0 = blockIdx.x * 128;
    const int tid = threadIdx.x, w = tid >> 6, lane = tid & 63;
    const int lm = lane & 15, lg = lane >> 4;
    bf16x8 qf[2][2];
#pragma unroll
    for (int qc = 0; qc < 2; ++qc) {
        const __bf16* qp = Q + (size_t)(q0 + w * 32 + qc * 16 + lm) * ldq + h * 64;
        qf[qc][0] = *(const bf16x8*)(qp + lg * 8);
        qf[qc][1] = *(const bf16x8*)(qp + 32 + lg * 8);
#pragma unroll
        for (int hh = 0; hh < 2; ++hh) {
            bf16x8 t = qf[qc][hh];
#pragma unroll
            for (int i = 0; i < 8; ++i) t[i] = (__bf16)((float)t[i] * 0.1803368801f);
            qf[qc][hh] = t;
        }
    }
    bf16x8 ones8;
#pragma unroll
    for (int i = 0; i < 8; ++i) ones8[i] = (__bf16)1.f;
    f32x4 o_[4][2] = {};
    f32x4 l_[2] = {};
    for (int kt = 0; kt < S / 64; ++kt) {
        __syncthreads();
#pragma unroll
        for (int i = 0; i < 2; ++i) {
            int c = i * 256 + tid;
            int rr = c >> 3, cc = (c & 7) * 8;
            *(uint4*)(Kt + rr * LDT + cc) =
                *(const uint4*)(Kg + (size_t)(kt * 64 + rr) * ldk + h * 64 + cc);
            *(uint4*)(Vt + rr * LDT + cc) =
                *(const uint4*)(VT + (size_t)(h * 64 + rr) * S + kt * 64 + cc);
        }
        __syncthreads();
        P8 pb[2][2];
#pragma unroll
        for (int mt = 0; mt < 4; ++mt) {
            bf16x8 kf0 = *(const bf16x8*)(Kt + (mt * 16 + lm) * LDT + lg * 8);
            bf16x8 kf1 = *(const bf16x8*)(Kt + (mt * 16 + lm) * LDT + 32 + lg * 8);
#pragma unroll
            for (int qc = 0; qc < 2; ++qc) {
                f32x4 s = (f32x4){0.f, 0.f, 0.f, 0.f};
                s = MFMA(kf0, qf[qc][0], s);
                s = MFMA(kf1, qf[qc][1], s);
                sh4 e = pk4(EXP2(s[0]), EXP2(s[1]), EXP2(s[2]), EXP2(s[3]));
                if (mt & 1) pb[mt >> 1][qc].p.hi = e;
                else        pb[mt >> 1][qc].p.lo = e;
            }
        }
#pragma unroll
        for (int mtd = 0; mtd < 4; ++mtd) {
            const __bf16* vrow = Vt + (mtd * 16 + lm) * LDT;
#pragma unroll
            for (int cp = 0; cp < 2; ++cp) {
                P8 va;
                va.p.lo = *(const sh4*)(vrow + cp * 32 + lg * 4);
                va.p.hi = *(const sh4*)(vrow + cp * 32 + 16 + lg * 4);
                bf16x8 vab = __builtin_bit_cast(bf16x8, va.v);
                o_[mtd][0] = MFMA(vab, __builtin_bit_cast(bf16x8, pb[cp][0].v), o_[mtd][0]);
                o_[mtd][1] = MFMA(vab, __builtin_bit_cast(bf16x8, pb[cp][1].v), o_[mtd][1]);
            }
        }
#pragma unroll
        for (int cp = 0; cp < 2; ++cp) {
            l_[0] = MFMA(ones8, __builtin_bit_cast(bf16x8, pb[cp][0].v), l_[0]);
            l_[1] = MFMA(ones8, __builtin_bit_cast(bf16x8, pb[cp][1].v), l_[1]);
        }
    }
    __syncthreads();
    float inv[2] = {1.f / l_[0][0], 1.f / l_[1][0]};
#pragma unroll
    for (int qc = 0; qc < 2; ++qc)
#pragma unroll
        for (int mtd = 0; mtd < 4; ++mtd)
#pragma unroll
            for (int r = 0; r < 4; ++r)
                lds[(w * 32 + qc * 16 + lm) * LDT + mtd * 16 + lg * 4 + r] =
                    (__bf16)(o_[mtd][qc][r] * inv[qc]);
    __syncthreads();
    int row = tid >> 1, cb = (tid & 1) * 32;
#pragma unroll
    for (int b = 0; b < 4; ++b)
        *(uint4*)(ctx + (size_t)(q0 + row) * D + h * 64 + cb + b * 8) =
            *(const uint4*)(lds + row * LDT + cb + b * 8);
}

// ---------------------------------------------------------------------------
extern "C" void kernel_launch(void* const* d_in, const int* in_sizes, int n_in,
                              void* d_out, int out_size, void* d_ws, size_t ws_size,
                              hipStream_t stream) {
    const void* x    = d_in[0];
    const void* Wq   = d_in[1];
    const void* bq   = d_in[2];
    const void* Wk   = d_in[3];
    const void* bk   = d_in[4];
    const void* Wv   = d_in[5];
    const void* bv   = d_in[6];
    const void* Wo   = d_in[7];
    const void* bo   = d_in[8];
    const void* ln1a = d_in[9];
    const void* ln1b = d_in[10];
    const void* W1   = d_in[11];
    const void* b1   = d_in[12];
    const void* W2   = d_in[13];
    const void* b2   = d_in[14];
    const void* ln2a = d_in[15];
    const void* ln2b = d_in[16];

    constexpr size_t M1 = 1u << 20;
    __bf16* ws = (__bf16*)d_ws;
    float* flagF = (float*)ws;
    __bf16* bmir = ws;
    dim3 tb(32, 8);
    const bool big = ws_size >= (size_t)(32.25 * 2 * M1) + 4096;

    prep_k<<<1, 256, 0, stream>>>(Wq, flagF, bq, bk, bv, bo, b1, b2,
                                  ln1a, ln1b, ln2a, ln2b, bmir);

    if (big) {
        // peak 32.25M elems = 64.5 MB
        __bf16* WqT = ws + M1 / 4;
        __bf16* WkT = WqT + M1;
        __bf16* WvT = ws + 2 * M1 + M1 / 4;
        __bf16* WoT = ws + 3 * M1 + M1 / 4;
        __bf16* W2T = ws + M1 / 4;
        float* lpart = (float*)(ws + M1 / 4);
        __bf16* hb  = ws + 4 * M1 + M1 / 4;
        __bf16* h2  = hb;
        __bf16* QKb = ws + 8 * M1 + M1 / 4;
        __bf16* x2  = QKb;
        __bf16* W1T = ws + 12 * M1 + M1 / 4;
        __bf16* Kswz = ws + 16 * M1 + M1 / 4;
        __bf16* ctx  = Kswz;
        __bf16* Vswz = ws + 20 * M1 + M1 / 4;
        __bf16* Opart = ws + 24 * M1 + M1 / 4;
        __bf16* f1  = ws + 16 * M1 + M1 / 4;

        transpose4_cvt<<<dim3(32, 32, 4), tb, 0, stream>>>(Wq, Wk, Wv, Wo,
                                                           WqT, WkT, WvT, WoT, flagF);
        layernorm_k<<<1024, 256, 0, stream>>>(x, 1, flagF, hb, bmir + 10240, bmir + 10241);
        gemm_bt<<<dim3(16, 32), 256, 0, stream>>>(hb, 1024, WqT, 1024, bmir + 1024, nullptr,
                                                  nullptr, 0, flagF, QKb, 0, 4096, 2048, 1024, 0,
                                                  Kswz, 1);
        gemm_n64<<<dim3(64, 8), 256, 0, stream>>>(WvT, 1024, hb, 1024, nullptr, bmir + 3072,
                                                  nullptr, 0, flagF, nullptr, 0, 1024, 4096, 1024, 0,
                                                  Vswz, 2);
        attn_ks2<<<dim3(32, 16, 2), 256, 0, stream>>>(QKb, 2048, Kswz, Vswz, Opart, lpart);
        attn_comb<<<512, 256, 0, stream>>>(Opart, lpart, ctx);
        transpose_cvt<<<dim3(128, 32), tb, 0, stream>>>(W1, W1T, 1024, 4096, flagF);
        gemm_n64<<<dim3(16, 32), 256, 0, stream>>>(ctx, 1024, WoT, 1024, bmir + 4096, nullptr,
                                                   x, 2, flagF, x2, 0, 4096, 1024, 1024, 0,
                                                   nullptr, 0);
        transpose_cvt<<<dim3(32, 128), tb, 0, stream>>>(W2, W2T, 4096, 1024, flagF);
        layernorm_k<<<1024, 256, 0, stream>>>(x2, 0, flagF, h2, bmir + 10242, bmir + 10243);
        gemm_bt<<<dim3(32, 32), 256, 0, stream>>>(h2, 1024, W1T, 1024, bmir + 5120, nullptr,
                                                  nullptr, 0, flagF, f1, 0, 4096, 4096, 1024, 1,
                                                  nullptr, 0);
        gemm_n64<<<dim3(16, 32), 256, 0, stream>>>(f1, 4096, W2T, 4096, bmir + 9216, nullptr,
                                                   x2, 1, flagF, d_out, 1, 4096, 1024, 4096, 0,
                                                   nullptr, 0);
    } else {
        // chunked fallback (r6), peak 46.5 MB
        constexpr size_t Qn = 1u << 18;
        __bf16* WqT = ws + Qn;
        __bf16* WoT = WqT;
        __bf16* WkT = ws + 5 * Qn;
        __bf16* WvT = ws + 9 * Qn;
        __bf16* hb  = ws + 13 * Qn;
        __bf16* f1q = hb;
        __bf16* ctx = ws + 29 * Qn;
        __bf16* W2T = ctx;
        __bf16* QKb = ws + 45 * Qn;
        __bf16* x2  = QKb;
        __bf16* Kb  = ws + 61 * Qn;
        __bf16* h2  = Kb;
        __bf16* VTb = ws + 77 * Qn;
        __bf16* W1T = VTb;
        transpose_cvt<<<dim3(32, 32), tb, 0, stream>>>(Wq, WqT, 1024, 1024, flagF);
        transpose_cvt<<<dim3(32, 32), tb, 0, stream>>>(Wk, WkT, 1024, 1024, flagF);
        transpose_cvt<<<dim3(32, 32), tb, 0, stream>>>(Wv, WvT, 1024, 1024, flagF);
        layernorm_k<<<1024, 256, 0, stream>>>(x, 1, flagF, hb, bmir + 10240, bmir + 10241);
        gemm_bt<<<dim3(8, 32), 256, 0, stream>>>(hb, 1024, WqT, 1024, bmir + 1024, nullptr,
                                                 nullptr, 0, flagF, QKb, 0, 4096, 1024, 1024, 0,
                                                 nullptr, 0);
        gemm_bt<<<dim3(8, 32), 256, 0, stream>>>(hb, 1024, WkT, 1024, bmir + 2048, nullptr,
                                                 nullptr, 0, flagF, Kb, 0, 4096, 1024, 1024, 0,
                                                 nullptr, 0);
        gemm_n64<<<dim3(64, 8), 256, 0, stream>>>(WvT, 1024, hb, 1024, nullptr, bmir + 3072,
                                                  nullptr, 0, flagF, VTb, 0, 1024, 4096, 1024, 0,
                                                  nullptr, 0);
        attn_v3<<<dim3(32, 16), 256, 0, stream>>>(QKb, 1024, Kb, 1024, VTb, ctx);
        transpose_cvt<<<dim3(32, 32), tb, 0, stream>>>(Wo, WoT, 1024, 1024, flagF);
        gemm_n64<<<dim3(16, 32), 256, 0, stream>>>(ctx, 1024, WoT, 1024, bmir + 4096, nullptr,
                                                   x, 2, flagF, x2, 0, 4096, 1024, 1024, 0,
                                                   nullptr, 0);
        layernorm_k<<<1024, 256, 0, stream>>>(x2, 0, flagF, h2, bmir + 10242, bmir + 10243);
        transpose_cvt<<<dim3(128, 32), tb, 0, stream>>>(W1, W1T, 1024, 4096, flagF);
        transpose_cvt<<<dim3(32, 128), tb, 0, stream>>>(W2, W2T, 4096, 1024, flagF);
        for (int ck = 0; ck < 2; ++ck) {
            gemm_bt<<<dim3(16, 32), 256, 0, stream>>>(h2, 1024, W1T + (size_t)ck * 2048 * 1024,
                                                      1024, bmir + 5120 + ck * 2048, nullptr,
                                                      nullptr, 0, flagF, f1q, 0, 4096, 2048, 1024, 1,
                                                      nullptr, 0);
            gemm_n64<<<dim3(16, 32), 256, 0, stream>>>(f1q, 2048, W2T + ck * 2048, 4096,
                                                       ck == 0 ? bmir + 9216 : nullptr, nullptr,
                                                       x2, 1, flagF, ck == 1 ? d_out : (void*)x2,
                                                       ck == 1 ? 1 : 0, 4096, 1024, 2048, 0,
                                                       nullptr, 0);
        }
    }
}

// Round 4
// 479.853 us; speedup vs baseline: 1.1210x; 1.0007x over previous
//
#include <hip/hip_runtime.h>
#include <hip/hip_bf16.h>

typedef __attribute__((ext_vector_type(8))) __bf16 bf16x8;
typedef __attribute__((ext_vector_type(4))) float f32x4;
typedef __attribute__((ext_vector_type(4))) short sh4;
typedef __attribute__((ext_vector_type(8))) short sh8;

#define MFMA(a, b, c) __builtin_amdgcn_mfma_f32_16x16x32_bf16(a, b, c, 0, 0, 0)

#if __has_builtin(__builtin_amdgcn_exp2f)
#define EXP2(x) __builtin_amdgcn_exp2f(x)
#else
#define EXP2(x) exp2f(x)
#endif

// K=32 B-frag / V-frag pairing: slot s = lg*8 + c*4 + r <-> kv-row c*16 + lg*4 + r.
// (kv is a contraction index; P and V use the same permutation, so this is exact.)
union P8 { struct { sh4 lo, hi; } p; sh8 v; };

// Packed f32->bf16 (v_cvt_pk_bf16_f32): 4 floats -> sh4 in 2 insts.
__device__ __forceinline__ sh4 pk4(float a, float b, float c, float d) {
    __hip_bfloat162 lo = __float22bfloat162_rn(float2{a, b});
    __hip_bfloat162 hi = __float22bfloat162_rn(float2{c, d});
    union { struct { __hip_bfloat162 lo, hi; } p; sh4 s; } u;
    u.p.lo = lo; u.p.hi = hi;
    return u.s;
}

__device__ __forceinline__ float ldany(const void* p, size_t i, bool f32) {
    return f32 ? ((const float*)p)[i] : (float)(((const __bf16*)p)[i]);
}

// ---------------------------------------------------------------------------
// Merged detect + small-conversions (one launch). offsets: bq 1024, bk 2048,
// bv 3072, bo 4096, b1 5120(4096), b2 9216, ln1a 10240..ln2b 10243.
__global__ void prep_k(const void* wq, float* flag,
                       const void* bq, const void* bk, const void* bv, const void* bo,
                       const void* b1, const void* b2,
                       const void* l1a, const void* l1b, const void* l2a, const void* l2b,
                       __bf16* dst) {
    __shared__ float red[256];
    __shared__ float fls;
    int tid = threadIdx.x;
    const __bf16* p = (const __bf16*)wq;
    float mx = 0.f;
    for (int i = tid; i < 1024; i += 256) {
        float v = (float)p[i];
        if (v != v) mx = 2.f;
        v = fabsf(v);
        if (v > mx) mx = v;
    }
    red[tid] = mx;
    __syncthreads();
    for (int s = 128; s > 0; s >>= 1) {
        if (tid < s) red[tid] = fmaxf(red[tid], red[tid + s]);
        __syncthreads();
    }
    if (tid == 0) { fls = (red[0] > 1.0f) ? 1.f : 0.f; *flag = fls; }
    __syncthreads();
    bool f32 = fls > 0.5f;
    const void* srcs[10] = {bq, bk, bv, bo, b1, b2, l1a, l1b, l2a, l2b};
    const int offs[10] = {1024, 2048, 3072, 4096, 5120, 9216, 10240, 10241, 10242, 10243};
    const int ns[10]   = {1024, 1024, 1024, 1024, 4096, 1024, 1, 1, 1, 1};
    for (int t = 0; t < 10; ++t)
        for (int j = tid; j < ns[t]; j += blockDim.x)
            dst[offs[t] + j] = (__bf16)ldany(srcs[t], j, f32);
}

// ---------------------------------------------------------------------------
__device__ __forceinline__ void tr_body(const void* in, __bf16* out, int R, int C, bool f32,
                                        int bx, int by, int x, int y) {
    __shared__ __bf16 t[32][33];
    for (int i = 0; i < 32; i += 8)
        t[y + i][x] = (__bf16)ldany(in, (size_t)(by + y + i) * C + bx + x, f32);
    __syncthreads();
    for (int i = 0; i < 32; i += 8)
        out[(size_t)(bx + y + i) * R + by + x] = t[x][y + i];
}

__global__ void transpose_cvt(const void* in, __bf16* out, int R, int C, const float* flag) {
    tr_body(in, out, R, C, *flag > 0.5f, blockIdx.x * 32, blockIdx.y * 32,
            threadIdx.x, threadIdx.y);
}

__global__ void transpose4_cvt(const void* i0, const void* i1, const void* i2, const void* i3,
                               __bf16* o0, __bf16* o1, __bf16* o2, __bf16* o3,
                               const float* flag) {
    const void* in = blockIdx.z == 0 ? i0 : blockIdx.z == 1 ? i1 : blockIdx.z == 2 ? i2 : i3;
    __bf16* out = blockIdx.z == 0 ? o0 : blockIdx.z == 1 ? o1 : blockIdx.z == 2 ? o2 : o3;
    tr_body(in, out, 1024, 1024, *flag > 0.5f, blockIdx.x * 32, blockIdx.y * 32,
            threadIdx.x, threadIdx.y);
}

// ---------------------------------------------------------------------------
__global__ __launch_bounds__(256) void layernorm_k(const void* x, int xmode, const float* flag,
                                                   __bf16* out,
                                                   const __bf16* alpha, const __bf16* beta) {
    int row = blockIdx.x * 4 + (threadIdx.x >> 6);
    int lane = threadIdx.x & 63;
    bool f32 = xmode && (*flag > 0.5f);
    float v[16];
    if (f32) {
        const float4* xr = (const float4*)((const float*)x + (size_t)row * 1024 + lane * 16);
#pragma unroll
        for (int q = 0; q < 4; ++q) {
            float4 r = xr[q];
            v[q * 4 + 0] = r.x; v[q * 4 + 1] = r.y; v[q * 4 + 2] = r.z; v[q * 4 + 3] = r.w;
        }
    } else {
        const __bf16* xr = (const __bf16*)x + (size_t)row * 1024 + lane * 16;
        bf16x8 h0 = *(const bf16x8*)xr;
        bf16x8 h1 = *(const bf16x8*)(xr + 8);
#pragma unroll
        for (int i = 0; i < 8; ++i) { v[i] = (float)h0[i]; v[8 + i] = (float)h1[i]; }
    }
    float s = 0.f, ss = 0.f;
#pragma unroll
    for (int i = 0; i < 16; ++i) { s += v[i]; ss += v[i] * v[i]; }
#pragma unroll
    for (int o = 1; o < 64; o <<= 1) { s += __shfl_xor(s, o); ss += __shfl_xor(ss, o); }
    float mu = s * (1.f / 1024.f);
    float var = (ss - 1024.f * mu * mu) * (1.f / 1023.f);
    float inv = 1.f / (sqrtf(var) + 1e-6f);
    float al = (float)alpha[0], be = (float)beta[0];
    bf16x8 o0, o1;
#pragma unroll
    for (int i = 0; i < 8; ++i) {
        o0[i] = (__bf16)((v[i] - mu) * inv * al + be);
        o1[i] = (__bf16)((v[8 + i] - mu) * inv * al + be);
    }
    __bf16* orow = out + (size_t)row * 1024;
    *(bf16x8*)(orow + lane * 16) = o0;
    *(bf16x8*)(orow + lane * 16 + 8) = o1;
}

// Swizzled-tile store helpers: 64x64 tiles, chunk (8 halves) XOR'd by row&7.
__device__ __forceinline__ void swz_store(__bf16* buf, int hh, int ktt, int rr2, int cc2,
                                          float v) {
    size_t off = (((size_t)hh * 64 + ktt) << 12) + rr2 * 64 +
                 (((cc2 >> 3) ^ (rr2 & 7)) << 3) + (cc2 & 7);
    buf[off] = (__bf16)v;
}

// ---------------------------------------------------------------------------
// GEMM 128x128 (256 thr), double-buffered with COUNTED vmcnt (T4):
//   stage(k+1) -> s_waitcnt vmcnt(4) [tile-k loads done, k+1 stays in flight]
//   -> raw s_barrier -> ds_read/MFMA -> lgkmcnt(0)+sched_fence -> raw s_barrier.
// Next-tile DMA spans the whole compute phase instead of being drained by
// __syncthreads' implicit vmcnt(0).  swz: 0 none; 1 = cols>=1024 -> swzbuf.
// ---------------------------------------------------------------------------
__global__ __launch_bounds__(256) void gemm_bt(const __bf16* __restrict__ A, int lda,
                                               const __bf16* __restrict__ Bt, int ldb,
                                               const __bf16* __restrict__ bias_n,
                                               const __bf16* __restrict__ bias_m,
                                               const void* res, int res_mode,
                                               const float* flag,
                                               void* C, int out_pf,
                                               int M, int N, int K, int relu,
                                               __bf16* swzbuf, int swz) {
    __shared__ __bf16 As[2][128 * 32];
    __shared__ __bf16 Bs[2][128 * 32];
    const int tid = threadIdx.x;
    const int m0 = blockIdx.y * 128;
    const int n0 = blockIdx.x * 128;
    const int w = tid >> 6, lane = tid & 63;
    const int wr = (w >> 1) * 64, wc = (w & 1) * 64;
    const int lm = lane & 15, lg = lane >> 4;
    const bool f32 = *flag > 0.5f;
    const bool rf32 = (res_mode == 2) && f32;
    const bool of32 = out_pf && f32;

    auto stage = [&](int buf, int k0) {
#pragma unroll
        for (int i = 0; i < 2; ++i) {
            int c = i * 256 + tid;
            int row = c >> 2, kk = (c & 3) * 8;
            __builtin_amdgcn_global_load_lds(
                (const __attribute__((address_space(1))) void*)(A + (size_t)(m0 + row) * lda + k0 + kk),
                (__attribute__((address_space(3))) void*)(As[buf] + c * 8), 16, 0, 0);
            __builtin_amdgcn_global_load_lds(
                (const __attribute__((address_space(1))) void*)(Bt + (size_t)(n0 + row) * ldb + k0 + kk),
                (__attribute__((address_space(3))) void*)(Bs[buf] + c * 8), 16, 0, 0);
        }
    };

    f32x4 acc[4][4] = {};
    stage(0, 0);
    int cur = 0;
    for (int k0 = 0; k0 < K; k0 += 32) {
        if (k0 + 32 < K) {
            stage(cur ^ 1, k0 + 32);
            asm volatile("s_waitcnt vmcnt(4)" ::: "memory");  // tile-cur landed; next in flight
        } else {
            asm volatile("s_waitcnt vmcnt(0)" ::: "memory");
        }
        __builtin_amdgcn_s_barrier();
        bf16x8 a[4], b[4];
#pragma unroll
        for (int t = 0; t < 4; ++t)
            a[t] = *(const bf16x8*)(As[cur] + (wr + t * 16 + lm) * 32 + lg * 8);
#pragma unroll
        for (int t = 0; t < 4; ++t)
            b[t] = *(const bf16x8*)(Bs[cur] + (wc + t * 16 + lm) * 32 + lg * 8);
#pragma unroll
        for (int mt = 0; mt < 4; ++mt)
#pragma unroll
            for (int nt = 0; nt < 4; ++nt)
                acc[mt][nt] = MFMA(a[mt], b[nt], acc[mt][nt]);
        asm volatile("s_waitcnt lgkmcnt(0)" ::: "memory");    // my ds_reads complete
        __builtin_amdgcn_sched_barrier(0);
        __builtin_amdgcn_s_barrier();                         // buf[cur] safe to overwrite
        cur ^= 1;
    }
#pragma unroll
    for (int mt = 0; mt < 4; ++mt) {
#pragma unroll
        for (int nt = 0; nt < 4; ++nt) {
            int col = n0 + wc + nt * 16 + lm;
            float bn = bias_n ? (float)bias_n[col] : 0.f;
#pragma unroll
            for (int r = 0; r < 4; ++r) {
                int row = m0 + wr + mt * 16 + lg * 4 + r;
                float vv = acc[mt][nt][r] + bn;
                if (bias_m) vv += (float)bias_m[row];
                if (relu) vv = fmaxf(vv, 0.f);
                if (swz == 1 && col >= 1024) {
                    swz_store(swzbuf, (col - 1024) >> 6, row >> 6, row & 63, (col - 1024) & 63, vv);
                } else if (swz == 2) {
                    swz_store(swzbuf, row >> 6, col >> 6, row & 63, col & 63, vv);
                } else {
                    size_t idx = (size_t)row * N + col;
                    if (res_mode) vv += rf32 ? ((const float*)res)[idx]
                                             : (float)(((const __bf16*)res)[idx]);
                    if (of32) ((float*)C)[idx] = vv;
                    else ((__bf16*)C)[idx] = (__bf16)vv;
                }
            }
        }
    }
}

// ---------------------------------------------------------------------------
// GEMM 128x64 (256 thr), BK=64, double-buffered, counted vmcnt(6) (T4).
// Chunk-XOR swizzle via pre-swizzled GLOBAL source (linear LDS dest) and on
// the ds_read side. 48 KiB LDS.
// ---------------------------------------------------------------------------
__global__ __launch_bounds__(256) void gemm_n64(const __bf16* __restrict__ A, int lda,
                                                const __bf16* __restrict__ Bt, int ldb,
                                                const __bf16* __restrict__ bias_n,
                                                const __bf16* __restrict__ bias_m,
                                                const void* res, int res_mode,
                                                const float* flag,
                                                void* C, int out_pf,
                                                int M, int N, int K, int relu,
                                                __bf16* swzbuf, int swz) {
    __shared__ __bf16 As[2][128 * 64];
    __shared__ __bf16 Bs[2][64 * 64];
    const int tid = threadIdx.x;
    const int m0 = blockIdx.y * 128;
    const int n0 = blockIdx.x * 64;
    const int w = tid >> 6, lane = tid & 63;
    const int wr = (w >> 1) * 64, wc = (w & 1) * 32;
    const int lm = lane & 15, lg = lane >> 4;
    const int sw = lm & 7;
    const bool f32 = *flag > 0.5f;
    const bool rf32 = (res_mode == 2) && f32;
    const bool of32 = out_pf && f32;

    auto stage = [&](int buf, int k0) {
#pragma unroll
        for (int i = 0; i < 4; ++i) {
            int c = i * 256 + tid;
            int row = c >> 3, ch = c & 7;
            __builtin_amdgcn_global_load_lds(
                (const __attribute__((address_space(1))) void*)(A + (size_t)(m0 + row) * lda + k0 + ((ch ^ (row & 7)) << 3)),
                (__attribute__((address_space(3))) void*)(As[buf] + c * 8), 16, 0, 0);
        }
#pragma unroll
        for (int i = 0; i < 2; ++i) {
            int c = i * 256 + tid;
            int row = c >> 3, ch = c & 7;
            __builtin_amdgcn_global_load_lds(
                (const __attribute__((address_space(1))) void*)(Bt + (size_t)(n0 + row) * ldb + k0 + ((ch ^ (row & 7)) << 3)),
                (__attribute__((address_space(3))) void*)(Bs[buf] + c * 8), 16, 0, 0);
        }
    };

    f32x4 acc[4][2] = {};
    stage(0, 0);
    int cur = 0;
    for (int k0 = 0; k0 < K; k0 += 64) {
        if (k0 + 64 < K) {
            stage(cur ^ 1, k0 + 64);
            asm volatile("s_waitcnt vmcnt(6)" ::: "memory");  // tile-cur landed; next in flight
        } else {
            asm volatile("s_waitcnt vmcnt(0)" ::: "memory");
        }
        __builtin_amdgcn_s_barrier();
        bf16x8 a[4][2], b[2][2];
#pragma unroll
        for (int t = 0; t < 4; ++t)
#pragma unroll
            for (int h = 0; h < 2; ++h)
                a[t][h] = *(const bf16x8*)(As[cur] + (wr + t * 16 + lm) * 64 + ((((h << 2) | lg) ^ sw) << 3));
#pragma unroll
        for (int t = 0; t < 2; ++t)
#pragma unroll
            for (int h = 0; h < 2; ++h)
                b[t][h] = *(const bf16x8*)(Bs[cur] + (wc + t * 16 + lm) * 64 + ((((h << 2) | lg) ^ sw) << 3));
#pragma unroll
        for (int mt = 0; mt < 4; ++mt)
#pragma unroll
            for (int nt = 0; nt < 2; ++nt) {
                acc[mt][nt] = MFMA(a[mt][0], b[nt][0], acc[mt][nt]);
                acc[mt][nt] = MFMA(a[mt][1], b[nt][1], acc[mt][nt]);
            }
        asm volatile("s_waitcnt lgkmcnt(0)" ::: "memory");
        __builtin_amdgcn_sched_barrier(0);
        __builtin_amdgcn_s_barrier();
        cur ^= 1;
    }
#pragma unroll
    for (int mt = 0; mt < 4; ++mt) {
#pragma unroll
        for (int nt = 0; nt < 2; ++nt) {
            int col = n0 + wc + nt * 16 + lm;
            float bn = bias_n ? (float)bias_n[col] : 0.f;
#pragma unroll
            for (int r = 0; r < 4; ++r) {
                int row = m0 + wr + mt * 16 + lg * 4 + r;
                float vv = acc[mt][nt][r] + bn;
                if (bias_m) vv += (float)bias_m[row];
                if (relu) vv = fmaxf(vv, 0.f);
                if (swz == 2) {
                    swz_store(swzbuf, row >> 6, col >> 6, row & 63, col & 63, vv);
                } else {
                    size_t idx = (size_t)row * N + col;
                    if (res_mode) vv += rf32 ? ((const float*)res)[idx]
                                             : (float)(((const __bf16*)res)[idx]);
                    if (of32) ((float*)C)[idx] = vv;
                    else ((__bf16*)C)[idx] = (__bf16)vv;
                }
            }
        }
    }
}

// ---------------------------------------------------------------------------
// Attention v7: K=32 PV via kv-permutation. P B-frags are register concats of
// the two pk4 outputs of adjacent 16-chunks; V A-frags read the SAME four sh4s
// per lane as the K=16 version, re-paired. PV+rowsum: 20 MFMAs/tile (was 48).
// ---------------------------------------------------------------------------
__global__ __launch_bounds__(256) void attn_ks2(const __bf16* __restrict__ Q, int ldq,
                                                const __bf16* __restrict__ Kswz,
                                                const __bf16* __restrict__ Vswz,
                                                __bf16* __restrict__ Opart,
                                                float* __restrict__ lpart) {
    constexpr int S = 4096;
    __shared__ __bf16 lds[2 * 8192];   // [buf][K tile 4096 | V tile 4096]
    const int h = blockIdx.y, z = blockIdx.z;
    const int q0 = blockIdx.x * 128;
    const int tid = threadIdx.x, w = tid >> 6, lane = tid & 63;
    const int lm = lane & 15, lg = lane >> 4;

    const __bf16* gK = Kswz + (((size_t)h * 64 + z * 32) << 12);
    const __bf16* gV = Vswz + (((size_t)h * 64 + z * 32) << 12);

    // Q B-frags (n=lm is q), pre-scaled by 0.125*log2e.
    bf16x8 qf[2][2];
#pragma unroll
    for (int qc = 0; qc < 2; ++qc) {
        const __bf16* qp = Q + (size_t)(q0 + w * 32 + qc * 16 + lm) * ldq + h * 64;
        qf[qc][0] = *(const bf16x8*)(qp + lg * 8);
        qf[qc][1] = *(const bf16x8*)(qp + 32 + lg * 8);
#pragma unroll
        for (int hh = 0; hh < 2; ++hh) {
            bf16x8 t = qf[qc][hh];
#pragma unroll
            for (int i = 0; i < 8; ++i) t[i] = (__bf16)((float)t[i] * 0.1803368801f);
            qf[qc][hh] = t;
        }
    }
    bf16x8 ones8;
#pragma unroll
    for (int i = 0; i < 8; ++i) ones8[i] = (__bf16)1.f;

    f32x4 o_[4][2] = {};
    f32x4 l_[2] = {};

    auto issue = [&](int t) {
        __bf16* dK = lds + (t & 1) * 8192;
        __bf16* dV = dK + 4096;
        const __bf16* sK = gK + ((size_t)t << 12);
        const __bf16* sV = gV + ((size_t)t << 12);
#pragma unroll
        for (int i = 0; i < 2; ++i) {
            int c = i * 256 + tid;
            __builtin_amdgcn_global_load_lds(
                (const __attribute__((address_space(1))) void*)(sK + c * 8),
                (__attribute__((address_space(3))) void*)(dK + c * 8), 16, 0, 0);
            __builtin_amdgcn_global_load_lds(
                (const __attribute__((address_space(1))) void*)(sV + c * 8),
                (__attribute__((address_space(3))) void*)(dV + c * 8), 16, 0, 0);
        }
    };
    issue(0);
    for (int t = 0; t < 32; ++t) {
        __syncthreads();                 // drains DMA for tile t; closes prev compute
        if (t < 31) issue(t + 1);        // in flight across this tile's compute
        const __bf16* Kt = lds + (t & 1) * 8192;
        const __bf16* Vt = Kt + 4096;

        P8 pb[2][2];
#pragma unroll
        for (int mt = 0; mt < 4; ++mt) {
            int rr = mt * 16 + lm;
            const __bf16* kr = Kt + rr * 64;
            bf16x8 kf0 = *(const bf16x8*)(kr + ((lg ^ (rr & 7)) << 3));
            bf16x8 kf1 = *(const bf16x8*)(kr + (((4 + lg) ^ (rr & 7)) << 3));
#pragma unroll
            for (int qc = 0; qc < 2; ++qc) {
                f32x4 s = (f32x4){0.f, 0.f, 0.f, 0.f};
                s = MFMA(kf0, qf[qc][0], s);
                s = MFMA(kf1, qf[qc][1], s);
                sh4 e = pk4(EXP2(s[0]), EXP2(s[1]), EXP2(s[2]), EXP2(s[3]));
                if (mt & 1) pb[mt >> 1][qc].p.hi = e;
                else        pb[mt >> 1][qc].p.lo = e;
            }
        }
#pragma unroll
        for (int mtd = 0; mtd < 4; ++mtd) {
            int rr = mtd * 16 + lm;
            const __bf16* vr = Vt + rr * 64;
#pragma unroll
            for (int cp = 0; cp < 2; ++cp) {
                int cbase = cp * 4 + (lg >> 1);
                P8 va;
                va.p.lo = *(const sh4*)(vr + ((cbase ^ (rr & 7)) << 3) + (lg & 1) * 4);
                va.p.hi = *(const sh4*)(vr + (((cbase + 2) ^ (rr & 7)) << 3) + (lg & 1) * 4);
                bf16x8 vab = __builtin_bit_cast(bf16x8, va.v);
                o_[mtd][0] = MFMA(vab, __builtin_bit_cast(bf16x8, pb[cp][0].v), o_[mtd][0]);
                o_[mtd][1] = MFMA(vab, __builtin_bit_cast(bf16x8, pb[cp][1].v), o_[mtd][1]);
            }
        }
#pragma unroll
        for (int cp = 0; cp < 2; ++cp) {
            l_[0] = MFMA(ones8, __builtin_bit_cast(bf16x8, pb[cp][0].v), l_[0]);
            l_[1] = MFMA(ones8, __builtin_bit_cast(bf16x8, pb[cp][1].v), l_[1]);
        }
    }

    // Unnormalized O^T -> lds[128][72] (packed 8B stores) -> coalesced store.
    __syncthreads();
#pragma unroll
    for (int qc = 0; qc < 2; ++qc) {
#pragma unroll
        for (int mtd = 0; mtd < 4; ++mtd) {
            sh4 ov = pk4(o_[mtd][qc][0], o_[mtd][qc][1], o_[mtd][qc][2], o_[mtd][qc][3]);
            *(sh4*)(lds + (w * 32 + qc * 16 + lm) * 72 + mtd * 16 + lg * 4) = ov;
        }
        if (lg == 0)
            lpart[(size_t)(h * 2 + z) * S + q0 + w * 32 + qc * 16 + lm] = l_[qc][0];
    }
    __syncthreads();
    __bf16* Ob = Opart + (((size_t)(h * 2 + z) * S + q0) << 6);
    int row = tid >> 1, co = (tid & 1) * 32;
#pragma unroll
    for (int b = 0; b < 4; ++b)
        *(uint4*)(Ob + row * 64 + co + b * 8) = *(const uint4*)(lds + row * 72 + co + b * 8);
}

__global__ __launch_bounds__(256) void attn_comb(const __bf16* __restrict__ Opart,
                                                 const float* __restrict__ lpart,
                                                 __bf16* __restrict__ ctx) {
    constexpr int S = 4096;
#pragma unroll
    for (int it = 0; it < 4; ++it) {
        int task = blockIdx.x * 1024 + it * 256 + threadIdx.x;  // (q, c8)
        int q = task >> 7, c8 = task & 127, h = c8 >> 3, d8 = (c8 & 7) * 8;
        const __bf16* p0 = Opart + (((size_t)(h * 2 + 0) * S + q) << 6) + d8;
        const __bf16* p1 = Opart + (((size_t)(h * 2 + 1) * S + q) << 6) + d8;
        float inv = 1.f / (lpart[(size_t)(h * 2 + 0) * S + q] + lpart[(size_t)(h * 2 + 1) * S + q]);
        bf16x8 a = *(const bf16x8*)p0, b = *(const bf16x8*)p1, o;
#pragma unroll
        for (int i = 0; i < 8; ++i) o[i] = (__bf16)(((float)a[i] + (float)b[i]) * inv);
        *(bf16x8*)(ctx + (size_t)q * 1024 + c8 * 8) = o;
    }
}

// ---------------------------------------------------------------------------
// r6 attention (padded-LDS, no split) — fallback path only. Same K=32 PV.
// ---------------------------------------------------------------------------
__global__ __launch_bounds__(256) void attn_v3(const __bf16* __restrict__ Q, int ldq,
                                               const __bf16* __restrict__ Kg, int ldk,
                                               const __bf16* __restrict__ VT,
                                               __bf16* __restrict__ ctx) {
    constexpr int S = 4096, D = 1024, LDT = 72;
    __shared__ __bf16 lds[128 * LDT];
    __bf16* Kt = lds;
    __bf16* Vt = lds + 64 * LDT;
    const int h = blockIdx.y;
    const int q0 = blockIdx.x * 128;
    const int tid = threadIdx.x, w = tid >> 6, lane = tid & 63;
    const int lm = lane & 15, lg = lane >> 4;
    bf16x8 qf[2][2];
#pragma unroll
    for (int qc = 0; qc < 2; ++qc) {
        const __bf16* qp = Q + (size_t)(q0 + w * 32 + qc * 16 + lm) * ldq + h * 64;
        qf[qc][0] = *(const bf16x8*)(qp + lg * 8);
        qf[qc][1] = *(const bf16x8*)(qp + 32 + lg * 8);
#pragma unroll
        for (int hh = 0; hh < 2; ++hh) {
            bf16x8 t = qf[qc][hh];
#pragma unroll
            for (int i = 0; i < 8; ++i) t[i] = (__bf16)((float)t[i] * 0.1803368801f);
            qf[qc][hh] = t;
        }
    }
    bf16x8 ones8;
#pragma unroll
    for (int i = 0; i < 8; ++i) ones8[i] = (__bf16)1.f;
    f32x4 o_[4][2] = {};
    f32x4 l_[2] = {};
    for (int kt = 0; kt < S / 64; ++kt) {
        __syncthreads();
#pragma unroll
        for (int i = 0; i < 2; ++i) {
            int c = i * 256 + tid;
            int rr = c >> 3, cc = (c & 7) * 8;
            *(uint4*)(Kt + rr * LDT + cc) =
                *(const uint4*)(Kg + (size_t)(kt * 64 + rr) * ldk + h * 64 + cc);
            *(uint4*)(Vt + rr * LDT + cc) =
                *(const uint4*)(VT + (size_t)(h * 64 + rr) * S + kt * 64 + cc);
        }
        __syncthreads();
        P8 pb[2][2];
#pragma unroll
        for (int mt = 0; mt < 4; ++mt) {
            bf16x8 kf0 = *(const bf16x8*)(Kt + (mt * 16 + lm) * LDT + lg * 8);
            bf16x8 kf1 = *(const bf16x8*)(Kt + (mt * 16 + lm) * LDT + 32 + lg * 8);
#pragma unroll
            for (int qc = 0; qc < 2; ++qc) {
                f32x4 s = (f32x4){0.f, 0.f, 0.f, 0.f};
                s = MFMA(kf0, qf[qc][0], s);
                s = MFMA(kf1, qf[qc][1], s);
                sh4 e = pk4(EXP2(s[0]), EXP2(s[1]), EXP2(s[2]), EXP2(s[3]));
                if (mt & 1) pb[mt >> 1][qc].p.hi = e;
                else        pb[mt >> 1][qc].p.lo = e;
            }
        }
#pragma unroll
        for (int mtd = 0; mtd < 4; ++mtd) {
            const __bf16* vrow = Vt + (mtd * 16 + lm) * LDT;
#pragma unroll
            for (int cp = 0; cp < 2; ++cp) {
                P8 va;
                va.p.lo = *(const sh4*)(vrow + cp * 32 + lg * 4);
                va.p.hi = *(const sh4*)(vrow + cp * 32 + 16 + lg * 4);
                bf16x8 vab = __builtin_bit_cast(bf16x8, va.v);
                o_[mtd][0] = MFMA(vab, __builtin_bit_cast(bf16x8, pb[cp][0].v), o_[mtd][0]);
                o_[mtd][1] = MFMA(vab, __builtin_bit_cast(bf16x8, pb[cp][1].v), o_[mtd][1]);
            }
        }
#pragma unroll
        for (int cp = 0; cp < 2; ++cp) {
            l_[0] = MFMA(ones8, __builtin_bit_cast(bf16x8, pb[cp][0].v), l_[0]);
            l_[1] = MFMA(ones8, __builtin_bit_cast(bf16x8, pb[cp][1].v), l_[1]);
        }
    }
    __syncthreads();
    float inv[2] = {1.f / l_[0][0], 1.f / l_[1][0]};
#pragma unroll
    for (int qc = 0; qc < 2; ++qc)
#pragma unroll
        for (int mtd = 0; mtd < 4; ++mtd)
#pragma unroll
            for (int r = 0; r < 4; ++r)
                lds[(w * 32 + qc * 16 + lm) * LDT + mtd * 16 + lg * 4 + r] =
                    (__bf16)(o_[mtd][qc][r] * inv[qc]);
    __syncthreads();
    int row = tid >> 1, cb = (tid & 1) * 32;
#pragma unroll
    for (int b = 0; b < 4; ++b)
        *(uint4*)(ctx + (size_t)(q0 + row) * D + h * 64 + cb + b * 8) =
            *(const uint4*)(lds + row * LDT + cb + b * 8);
}

// ---------------------------------------------------------------------------
extern "C" void kernel_launch(void* const* d_in, const int* in_sizes, int n_in,
                              void* d_out, int out_size, void* d_ws, size_t ws_size,
                              hipStream_t stream) {
    const void* x    = d_in[0];
    const void* Wq   = d_in[1];
    const void* bq   = d_in[2];
    const void* Wk   = d_in[3];
    const void* bk   = d_in[4];
    const void* Wv   = d_in[5];
    const void* bv   = d_in[6];
    const void* Wo   = d_in[7];
    const void* bo   = d_in[8];
    const void* ln1a = d_in[9];
    const void* ln1b = d_in[10];
    const void* W1   = d_in[11];
    const void* b1   = d_in[12];
    const void* W2   = d_in[13];
    const void* b2   = d_in[14];
    const void* ln2a = d_in[15];
    const void* ln2b = d_in[16];

    constexpr size_t M1 = 1u << 20;
    __bf16* ws = (__bf16*)d_ws;
    float* flagF = (float*)ws;
    __bf16* bmir = ws;
    dim3 tb(32, 8);
    const bool big = ws_size >= (size_t)(32.25 * 2 * M1) + 4096;

    prep_k<<<1, 256, 0, stream>>>(Wq, flagF, bq, bk, bv, bo, b1, b2,
                                  ln1a, ln1b, ln2a, ln2b, bmir);

    if (big) {
        // peak 32.25M elems = 64.5 MB
        __bf16* WqT = ws + M1 / 4;
        __bf16* WkT = WqT + M1;
        __bf16* WvT = ws + 2 * M1 + M1 / 4;
        __bf16* WoT = ws + 3 * M1 + M1 / 4;
        __bf16* W2T = ws + M1 / 4;
        float* lpart = (float*)(ws + M1 / 4);
        __bf16* hb  = ws + 4 * M1 + M1 / 4;
        __bf16* h2  = hb;
        __bf16* QKb = ws + 8 * M1 + M1 / 4;
        __bf16* x2  = QKb;
        __bf16* W1T = ws + 12 * M1 + M1 / 4;
        __bf16* Kswz = ws + 16 * M1 + M1 / 4;
        __bf16* ctx  = Kswz;
        __bf16* Vswz = ws + 20 * M1 + M1 / 4;
        __bf16* Opart = ws + 24 * M1 + M1 / 4;
        __bf16* f1  = ws + 16 * M1 + M1 / 4;

        transpose4_cvt<<<dim3(32, 32, 4), tb, 0, stream>>>(Wq, Wk, Wv, Wo,
                                                           WqT, WkT, WvT, WoT, flagF);
        layernorm_k<<<1024, 256, 0, stream>>>(x, 1, flagF, hb, bmir + 10240, bmir + 10241);
        gemm_bt<<<dim3(16, 32), 256, 0, stream>>>(hb, 1024, WqT, 1024, bmir + 1024, nullptr,
                                                  nullptr, 0, flagF, QKb, 0, 4096, 2048, 1024, 0,
                                                  Kswz, 1);
        gemm_n64<<<dim3(64, 8), 256, 0, stream>>>(WvT, 1024, hb, 1024, nullptr, bmir + 3072,
                                                  nullptr, 0, flagF, nullptr, 0, 1024, 4096, 1024, 0,
                                                  Vswz, 2);
        attn_ks2<<<dim3(32, 16, 2), 256, 0, stream>>>(QKb, 2048, Kswz, Vswz, Opart, lpart);
        attn_comb<<<512, 256, 0, stream>>>(Opart, lpart, ctx);
        transpose_cvt<<<dim3(128, 32), tb, 0, stream>>>(W1, W1T, 1024, 4096, flagF);
        gemm_n64<<<dim3(16, 32), 256, 0, stream>>>(ctx, 1024, WoT, 1024, bmir + 4096, nullptr,
                                                   x, 2, flagF, x2, 0, 4096, 1024, 1024, 0,
                                                   nullptr, 0);
        transpose_cvt<<<dim3(32, 128), tb, 0, stream>>>(W2, W2T, 4096, 1024, flagF);
        layernorm_k<<<1024, 256, 0, stream>>>(x2, 0, flagF, h2, bmir + 10242, bmir + 10243);
        gemm_bt<<<dim3(32, 32), 256, 0, stream>>>(h2, 1024, W1T, 1024, bmir + 5120, nullptr,
                                                  nullptr, 0, flagF, f1, 0, 4096, 4096, 1024, 1,
                                                  nullptr, 0);
        gemm_n64<<<dim3(16, 32), 256, 0, stream>>>(f1, 4096, W2T, 4096, bmir + 9216, nullptr,
                                                   x2, 1, flagF, d_out, 1, 4096, 1024, 4096, 0,
                                                   nullptr, 0);
    } else {
        // chunked fallback (r6), peak 46.5 MB
        constexpr size_t Qn = 1u << 18;
        __bf16* WqT = ws + Qn;
        __bf16* WoT = WqT;
        __bf16* WkT = ws + 5 * Qn;
        __bf16* WvT = ws + 9 * Qn;
        __bf16* hb  = ws + 13 * Qn;
        __bf16* f1q = hb;
        __bf16* ctx = ws + 29 * Qn;
        __bf16* W2T = ctx;
        __bf16* QKb = ws + 45 * Qn;
        __bf16* x2  = QKb;
        __bf16* Kb  = ws + 61 * Qn;
        __bf16* h2  = Kb;
        __bf16* VTb = ws + 77 * Qn;
        __bf16* W1T = VTb;
        transpose_cvt<<<dim3(32, 32), tb, 0, stream>>>(Wq, WqT, 1024, 1024, flagF);
        transpose_cvt<<<dim3(32, 32), tb, 0, stream>>>(Wk, WkT, 1024, 1024, flagF);
        transpose_cvt<<<dim3(32, 32), tb, 0, stream>>>(Wv, WvT, 1024, 1024, flagF);
        layernorm_k<<<1024, 256, 0, stream>>>(x, 1, flagF, hb, bmir + 10240, bmir + 10241);
        gemm_bt<<<dim3(8, 32), 256, 0, stream>>>(hb, 1024, WqT, 1024, bmir + 1024, nullptr,
                                                 nullptr, 0, flagF, QKb, 0, 4096, 1024, 1024, 0,
                                                 nullptr, 0);
        gemm_bt<<<dim3(8, 32), 256, 0, stream>>>(hb, 1024, WkT, 1024, bmir + 2048, nullptr,
                                                 nullptr, 0, flagF, Kb, 0, 4096, 1024, 1024, 0,
                                                 nullptr, 0);
        gemm_n64<<<dim3(64, 8), 256, 0, stream>>>(WvT, 1024, hb, 1024, nullptr, bmir + 3072,
                                                  nullptr, 0, flagF, VTb, 0, 1024, 4096, 1024, 0,
                                                  nullptr, 0);
        attn_v3<<<dim3(32, 16), 256, 0, stream>>>(QKb, 1024, Kb, 1024, VTb, ctx);
        transpose_cvt<<<dim3(32, 32), tb, 0, stream>>>(Wo, WoT, 1024, 1024, flagF);
        gemm_n64<<<dim3(16, 32), 256, 0, stream>>>(ctx, 1024, WoT, 1024, bmir + 4096, nullptr,
                                                   x, 2, flagF, x2, 0, 4096, 1024, 1024, 0,
                                                   nullptr, 0);
        layernorm_k<<<1024, 256, 0, stream>>>(x2, 0, flagF, h2, bmir + 10242, bmir + 10243);
        transpose_cvt<<<dim3(128, 32), tb, 0, stream>>>(W1, W1T, 1024, 4096, flagF);
        transpose_cvt<<<dim3(32, 128), tb, 0, stream>>>(W2, W2T, 4096, 1024, flagF);
        for (int ck = 0; ck < 2; ++ck) {
            gemm_bt<<<dim3(16, 32), 256, 0, stream>>>(h2, 1024, W1T + (size_t)ck * 2048 * 1024,
                                                      1024, bmir + 5120 + ck * 2048, nullptr,
                                                      nullptr, 0, flagF, f1q, 0, 4096, 2048, 1024, 1,
                                                      nullptr, 0);
            gemm_n64<<<dim3(16, 32), 256, 0, stream>>>(f1q, 2048, W2T + ck * 2048, 4096,
                                                       ck == 0 ? bmir + 9216 : nullptr, nullptr,
                                                       x2, 1, flagF, ck == 1 ? d_out : (void*)x2,
                                                       ck == 1 ? 1 : 0, 4096, 1024, 2048, 0,
                                                       nullptr, 0);
        }
    }
}